// Round 5
// baseline (213.747 us; speedup 1.0000x reference)
//
#include <hip/hip_runtime.h>
#include <hip/hip_bf16.h>
#include <math.h>

#define P_N   2048
#define B_N   10000
#define NB    15
#define MROWS (P_N * NB)   // 30720
#define SPLIT 5
#define BPB   (B_N / SPLIT)  // 2000 boundary points per scan block

typedef __bf16 bf16x8 __attribute__((ext_vector_type(8)));
typedef float  f32x4  __attribute__((ext_vector_type(4)));

__device__ __forceinline__ float bf2f(unsigned short u) {
    union { unsigned int i; float f; } v; v.i = ((unsigned int)u) << 16; return v.f;
}
__device__ __forceinline__ unsigned short f2bf(float f) {
    union { float f; unsigned int i; } v; v.f = f;
    unsigned int i = v.i;
    i += 0x7FFFu + ((i >> 16) & 1u);
    return (unsigned short)(i >> 16);
}
__device__ __forceinline__ void gld_lds16(const unsigned short* g, unsigned short* l) {
    __builtin_amdgcn_global_load_lds(
        (const __attribute__((address_space(1))) unsigned int*)g,
        (__attribute__((address_space(3))) unsigned int*)l, 16, 0, 0);
}

// ---- K0: tiled transpose W1/W2 -> bf16 [N][K]; zero stats; init keys --------
__global__ __launch_bounds__(256) void k_prep(const float* __restrict__ W1,
        const float* __restrict__ W2, unsigned short* __restrict__ w1t,
        unsigned short* __restrict__ w2t, float* __restrict__ stats,
        unsigned long long* __restrict__ keys) {
    int blk = blockIdx.x, tid = threadIdx.x;
    if (blk < 144) {
        __shared__ unsigned short t[64][65];
        const float* W; unsigned short* O; int NC, K, tr, tc;
        if (blk < 16) { W = W1; O = w1t; NC = 512; K = 128; tr = blk & 1; tc = blk >> 1; }
        else { int b = blk - 16; W = W2; O = w2t; NC = 1024; K = 512; tr = b & 7; tc = b >> 3; }
        int r0 = tr * 64, c0 = tc * 64;
        int cx = tid & 63, rg = tid >> 6;
#pragma unroll
        for (int i = 0; i < 16; ++i) {
            int r = rg * 16 + i;
            t[r][cx] = f2bf(W[(size_t)(r0 + r) * NC + c0 + cx]);
        }
        __syncthreads();
#pragma unroll
        for (int i = 0; i < 16; ++i) {
            int n = rg * 16 + i;
            O[(size_t)(c0 + n) * K + r0 + cx] = t[cx][n];
        }
    } else {
        int idx = (blk - 144) * 256 + tid;        // 120 blocks: 30720 keys
        if (idx < MROWS) keys[idx] = ~0ull;
        if (idx < 3072) stats[idx] = 0.0f;
    }
}

// ---- K1a: scan boundary points, per-bin min via packed u64 atomicMin --------
__global__ __launch_bounds__(256) void k_scan(
        const float* __restrict__ end_pos, const float* __restrict__ rel_pos,
        const float* __restrict__ bpts, unsigned long long* __restrict__ keys) {
    __shared__ unsigned long long s_key[NB];
    int tid = threadIdx.x;
    int p = blockIdx.x / SPLIT, part = blockIdx.x % SPLIT;
    if (tid < NB) s_key[tid] = ~0ull;
    __syncthreads();

    float ex = end_pos[2 * p], ey = end_pos[2 * p + 1];
    float rx = rel_pos[2 * p], ry = rel_pos[2 * p + 1];
    float rr = rx * rx + ry * ry;
    float c, s;
    if (rr > 0.0f) { float inv = 1.0f / sqrtf(rr); c = rx * inv; s = ry * inv; }
    else           { c = 1.0f; s = 0.0f; }

    const float T0 = -4.704630109f, T1 = -2.246036774f, T2 = -1.376381920f,
                T3 = -0.900404044f, T4 = -0.577350269f, T5 = -0.324919696f,
                T6 = -0.105104235f, T7 =  0.105104235f, T8 =  0.324919696f,
                T9 =  0.577350269f, T10 = 0.900404044f, T11 = 1.376381920f,
                T12 = 2.246036774f, T13 = 4.704630109f;

    const float2* bp2 = (const float2*)bpts;
    int bstart = part * BPB;
    for (int b = bstart + tid; b < bstart + BPB; b += 256) {
        float2 pt = bp2[b];
        float dx = pt.x - ex, dy = pt.y - ey;
        float xb = dx * c + dy * s;
        float yb = dy * c - dx * s;
        float r2 = xb * xb + yb * yb;
        bool v3 = yb > T7 * xb;
        float ta = v3 ? T11 : T3;
        bool v2 = yb > ta * xb;
        float tb = v3 ? (v2 ? T13 : T9) : (v2 ? T5 : T1);
        bool v1 = yb > tb * xb;
        float tc = v3 ? (v2 ? (v1 ? 3.0e38f : T12) : (v1 ? T10 : T8))
                      : (v2 ? (v1 ? T6 : T4)       : (v1 ? T2 : T0));
        bool v0 = yb > tc * xb;
        int bin = (v3 ? 8 : 0) + (v2 ? 4 : 0) + (v1 ? 2 : 0) + (v0 ? 1 : 0);
        if (xb > 0.0f) {
            unsigned long long key =
                ((unsigned long long)__float_as_uint(r2) << 32) | (unsigned int)b;
            atomicMin(&s_key[bin], key);
        }
    }
    __syncthreads();
    if (tid < NB) atomicMin(&keys[p * NB + tid], s_key[tid]);
}

// ---- K1b: choose point/fallback, build X = [emb(64) | h(64)] per (p,cell) ---
__global__ __launch_bounds__(256) void k_assemble(
        const unsigned long long* __restrict__ keys,
        const float* __restrict__ end_pos, const float* __restrict__ rel_pos,
        const float* __restrict__ bpts, const float* __restrict__ Wsp,
        const float* __restrict__ bsp, const float* __restrict__ h,
        unsigned short* __restrict__ X) {
    __shared__ float2 s_rel[NB];
    int p = blockIdx.x, tid = threadIdx.x;
    if (tid < NB) {
        float ex = end_pos[2 * p], ey = end_pos[2 * p + 1];
        unsigned long long key = keys[p * NB + tid];
        float r = sqrtf(__uint_as_float((unsigned int)(key >> 32)));
        float relx, rely;
        if (r <= 2.0f) {
            int b = (int)(key & 0xFFFFFFFFu);
            relx = bpts[2 * b] - ex; rely = bpts[2 * b + 1] - ey;
        } else {
            float rx = rel_pos[2 * p], ry = rel_pos[2 * p + 1];
            float rr = rx * rx + ry * ry;
            float c, s;
            if (rr > 0.0f) { float inv = 1.0f / sqrtf(rr); c = rx * inv; s = ry * inv; }
            else           { c = 1.0f; s = 0.0f; }
            float th = ((float)tid + 0.5f) * (float)(M_PI / 15.0) - (float)(M_PI / 2.0);
            float xc = 2.0f * cosf(th), yc = 2.0f * sinf(th);
            relx = xc * c - yc * s;
            rely = xc * s + yc * c;
        }
        s_rel[tid] = make_float2(relx, rely);
    }
    __syncthreads();
    if (tid < NB * 16) {
        int cell = tid >> 4, e0 = (tid & 15) * 8;
        float2 rel = s_rel[cell];
        unsigned short ubuf[8];
        if (e0 < 64) {
            float4 w0a = *(const float4*)(Wsp + e0),      w0b = *(const float4*)(Wsp + e0 + 4);
            float4 w1a = *(const float4*)(Wsp + 64 + e0), w1b = *(const float4*)(Wsp + 64 + e0 + 4);
            float4 bba = *(const float4*)(bsp + e0),      bbb = *(const float4*)(bsp + e0 + 4);
            float w0[8] = {w0a.x,w0a.y,w0a.z,w0a.w,w0b.x,w0b.y,w0b.z,w0b.w};
            float w1[8] = {w1a.x,w1a.y,w1a.z,w1a.w,w1b.x,w1b.y,w1b.z,w1b.w};
            float bb[8] = {bba.x,bba.y,bba.z,bba.w,bbb.x,bbb.y,bbb.z,bbb.w};
#pragma unroll
            for (int j = 0; j < 8; ++j)
                ubuf[j] = f2bf(rel.x * w0[j] + rel.y * w1[j] + bb[j]);
        } else {
            float4 ha = *(const float4*)(h + p * 64 + (e0 - 64));
            float4 hb = *(const float4*)(h + p * 64 + (e0 - 64) + 4);
            float hv[8] = {ha.x,ha.y,ha.z,ha.w,hb.x,hb.y,hb.z,hb.w};
#pragma unroll
            for (int j = 0; j < 8; ++j) ubuf[j] = f2bf(hv[j]);
        }
        *(uint4*)(X + ((size_t)p * NB + cell) * 128 + e0) = *(uint4*)ubuf;
    }
}

// ---- GEMM: 128x128 tile, BK=32, double-buffered gload_lds (2-phase pipeline),
//      bank-uniform [kseg][row][8] LDS chunks, LDS-staged C epilogue ----------
template<int K, bool STATS>
__global__ __launch_bounds__(256) void k_gemm(
        const unsigned short* __restrict__ A, const unsigned short* __restrict__ Bt,
        const float* __restrict__ bias, unsigned short* __restrict__ C,
        int M, int N, float* __restrict__ osum, float* __restrict__ osq) {
    __shared__ __align__(16) unsigned short lds[16384];  // 2 bufs × (A 8KB | B 8KB)
    int tid = threadIdx.x;
    int tiles_m = M >> 7;
    int bm = blockIdx.x % tiles_m, bn = blockIdx.x / tiles_m;
    int row0 = bm << 7, col0 = bn << 7;
    int lane = tid & 63, wave = tid >> 6;
    int wr = wave >> 1, wc = wave & 1;
    int frow = lane & 15, kq = lane >> 4;

    f32x4 zero = {0.f, 0.f, 0.f, 0.f};
    f32x4 acc[4][4];
#pragma unroll
    for (int i = 0; i < 4; ++i)
#pragma unroll
        for (int j = 0; j < 4; ++j) acc[i][j] = zero;

    // staging: lane -> (row = lane&15, kseg = lane>>4); wave w covers rows
    // [w*32, w*32+32) as two 16-row chunks. Chunk LDS layout [kseg][row][8]
    // (1KB, linear in lane order) -> fragment ds_reads are bank-uniform.
    const unsigned short* gA  = A  + (size_t)(row0 + wave * 32 + frow) * K + kq * 8;
    const unsigned short* gB  = Bt + (size_t)(col0 + wave * 32 + frow) * K + kq * 8;
    const unsigned short* gA2 = gA + (size_t)16 * K;
    const unsigned short* gB2 = gB + (size_t)16 * K;

    // prologue: stage k-tile 0 into buffer 0
    gld_lds16(gA,  lds + wave * 1024);
    gld_lds16(gA2, lds + wave * 1024 + 512);
    gld_lds16(gB,  lds + 4096 + wave * 1024);
    gld_lds16(gB2, lds + 4096 + wave * 1024 + 512);

    constexpr int NT = K / 32;
#pragma unroll
    for (int t = 0; t < NT; ++t) {
        __syncthreads();                       // buf[t&1] ready (vmcnt+lgkm drained)
        if (t + 1 < NT) {                      // issue next tile into other buffer
            unsigned short* d = lds + ((t + 1) & 1) * 8192;
            int ko = (t + 1) * 32;
            gld_lds16(gA + ko,  d + wave * 1024);
            gld_lds16(gA2 + ko, d + wave * 1024 + 512);
            gld_lds16(gB + ko,  d + 4096 + wave * 1024);
            gld_lds16(gB2 + ko, d + 4096 + wave * 1024 + 512);
        }
        const unsigned short* buf = lds + (t & 1) * 8192;
        bf16x8 af[4], bfv[4];
#pragma unroll
        for (int i = 0; i < 4; ++i) {
            af[i]  = *(const bf16x8*)&buf[(wr * 4 + i) * 512 + kq * 128 + frow * 8];
            bfv[i] = *(const bf16x8*)&buf[4096 + (wc * 4 + i) * 512 + kq * 128 + frow * 8];
        }
#pragma unroll
        for (int i = 0; i < 4; ++i)
#pragma unroll
            for (int j = 0; j < 4; ++j)
                acc[i][j] = __builtin_amdgcn_mfma_f32_16x16x32_bf16(af[i], bfv[j], acc[i][j], 0, 0, 0);
    }

    // epilogue: two 64-row bands; stage f2bf(acc+bias) in LDS, store coalesced
    unsigned short* ldsC = lds;
    int rbase = (lane >> 4) << 2;
#pragma unroll
    for (int ci = 0; ci < 2; ++ci) {
        __syncthreads();
        if (wr == ci) {
#pragma unroll
            for (int j = 0; j < 4; ++j) {
                int col = col0 + wc * 64 + j * 16 + frow;
                float bv = bias[col];
                float csum = 0.f, csq = 0.f;
#pragma unroll
                for (int i = 0; i < 4; ++i) {
#pragma unroll
                    for (int r = 0; r < 4; ++r) {
                        float y = acc[i][j][r] + bv;
                        ldsC[(i * 16 + rbase + r) * 136 + wc * 64 + j * 16 + frow] = f2bf(y);
                        if (STATS) { csum += y; csq = fmaf(y, y, csq); }
                    }
                }
                if (STATS) {
                    csum += __shfl_xor(csum, 16); csum += __shfl_xor(csum, 32);
                    csq  += __shfl_xor(csq, 16);  csq  += __shfl_xor(csq, 32);
                    if (lane < 16) { atomicAdd(&osum[col], csum); atomicAdd(&osq[col], csq); }
                }
            }
        }
        __syncthreads();
#pragma unroll
        for (int it = 0; it < 4; ++it) {
            int t = it * 256 + tid;
            int brow = t >> 4, seg = t & 15;
            *(uint4*)(C + (size_t)(row0 + ci * 64 + brow) * N + col0 + seg * 8) =
                *(const uint4*)&ldsC[brow * 136 + seg * 8];
        }
    }
}

// ---- finalize: per-column affine coefficients -------------------------------
__global__ void k_finalize(const float* __restrict__ s, const float* __restrict__ q,
                           const float* __restrict__ g, const float* __restrict__ be,
                           float* __restrict__ sc, float* __restrict__ sh, int Ncols) {
    int i = blockIdx.x * 256 + threadIdx.x;
    if (i >= Ncols) return;
    const float invN = 1.0f / (float)MROWS;
    float m = s[i] * invN;
    float v = q[i] * invN - m * m;
    float k = g[i] * rsqrtf(v + 1e-5f);
    sc[i] = k;
    sh[i] = be[i] - m * k;
}

// ---- BN + ReLU, in place, column-resident streaming (N=512) -----------------
__global__ __launch_bounds__(256) void k_bnrelu(unsigned short* __restrict__ Y,
        const float* __restrict__ sc, const float* __restrict__ sh) {
    int tid = threadIdx.x;
    int seg  = tid & 63;                 // 64 uint4 segments per 512-col row
    int roff = tid >> 6;                 // 4 row-phases
    int r0 = blockIdx.x * 32;
    float4 sc0 = *(const float4*)(sc + seg * 8);
    float4 sc1 = *(const float4*)(sc + seg * 8 + 4);
    float4 sh0 = *(const float4*)(sh + seg * 8);
    float4 sh1 = *(const float4*)(sh + seg * 8 + 4);
    float scv[8] = {sc0.x, sc0.y, sc0.z, sc0.w, sc1.x, sc1.y, sc1.z, sc1.w};
    float shv[8] = {sh0.x, sh0.y, sh0.z, sh0.w, sh1.x, sh1.y, sh1.z, sh1.w};
    for (int r = r0 + roff; r < r0 + 32; r += 4) {
        unsigned short* p = Y + (size_t)r * 512 + seg * 8;
        uint4 v = *(const uint4*)p;
        unsigned short* u = (unsigned short*)&v;
#pragma unroll
        for (int j = 0; j < 8; ++j) {
            float x = fmaf(bf2f(u[j]), scv[j], shv[j]);
            u[j] = f2bf(fmaxf(x, 0.0f));
        }
        *(uint4*)p = v;
    }
}

// ---- BN2 (inline coeffs) + ReLU + max over 15 cells -> out (f32) ------------
__global__ void k_bnmax(const unsigned short* __restrict__ Y2, const float* __restrict__ s2,
                        const float* __restrict__ q2, const float* __restrict__ g2,
                        const float* __restrict__ be2, float* __restrict__ out) {
    int idx = blockIdx.x * 256 + threadIdx.x;      // 2048*128 threads
    int p = idx >> 7, cb = idx & 127;
    int c0 = cb << 3;
    const float invN = 1.0f / (float)MROWS;
    float4 sa = *(const float4*)(s2 + c0),  sb = *(const float4*)(s2 + c0 + 4);
    float4 qa = *(const float4*)(q2 + c0),  qb = *(const float4*)(q2 + c0 + 4);
    float4 ga = *(const float4*)(g2 + c0),  gb = *(const float4*)(g2 + c0 + 4);
    float4 ea = *(const float4*)(be2 + c0), eb = *(const float4*)(be2 + c0 + 4);
    float sv[8] = {sa.x,sa.y,sa.z,sa.w,sb.x,sb.y,sb.z,sb.w};
    float qv[8] = {qa.x,qa.y,qa.z,qa.w,qb.x,qb.y,qb.z,qb.w};
    float gv[8] = {ga.x,ga.y,ga.z,ga.w,gb.x,gb.y,gb.z,gb.w};
    float ev[8] = {ea.x,ea.y,ea.z,ea.w,eb.x,eb.y,eb.z,eb.w};
    float scv[8], shv[8];
#pragma unroll
    for (int j = 0; j < 8; ++j) {
        float m = sv[j] * invN;
        float v = qv[j] * invN - m * m;
        float k = gv[j] * rsqrtf(v + 1e-5f);
        scv[j] = k; shv[j] = ev[j] - m * k;
    }
    float mx[8];
#pragma unroll
    for (int j = 0; j < 8; ++j) mx[j] = -3.0e38f;
#pragma unroll
    for (int cell = 0; cell < NB; ++cell) {
        uint4 v = *(const uint4*)(Y2 + ((size_t)(p * NB + cell)) * 1024 + c0);
        const unsigned short* u = (const unsigned short*)&v;
#pragma unroll
        for (int j = 0; j < 8; ++j) {
            float x = fmaf(bf2f(u[j]), scv[j], shv[j]);
            mx[j] = fmaxf(mx[j], x);
        }
    }
    float4 o0, o1;
    o0.x = fmaxf(mx[0], 0.f); o0.y = fmaxf(mx[1], 0.f);
    o0.z = fmaxf(mx[2], 0.f); o0.w = fmaxf(mx[3], 0.f);
    o1.x = fmaxf(mx[4], 0.f); o1.y = fmaxf(mx[5], 0.f);
    o1.z = fmaxf(mx[6], 0.f); o1.w = fmaxf(mx[7], 0.f);
    *(float4*)(out + (size_t)p * 1024 + c0)     = o0;
    *(float4*)(out + (size_t)p * 1024 + c0 + 4) = o1;
}

extern "C" void kernel_launch(void* const* d_in, const int* in_sizes, int n_in,
                              void* d_out, int out_size, void* d_ws, size_t ws_size,
                              hipStream_t stream) {
    const float* h       = (const float*)d_in[0];
    const float* end_pos = (const float*)d_in[1];
    const float* rel_pos = (const float*)d_in[2];
    const float* bpts    = (const float*)d_in[3];
    const float* Wsp     = (const float*)d_in[4];
    const float* bsp     = (const float*)d_in[5];
    const float* W1      = (const float*)d_in[6];
    const float* b1      = (const float*)d_in[7];
    const float* g1      = (const float*)d_in[8];
    const float* be1     = (const float*)d_in[9];
    const float* W2      = (const float*)d_in[10];
    const float* b2      = (const float*)d_in[11];
    const float* g2      = (const float*)d_in[12];
    const float* be2     = (const float*)d_in[13];
    float* out = (float*)d_out;

    char* ws = (char*)d_ws;
    float* s1  = (float*)ws;                 // zeroed by k_prep (first 3072 f32)
    float* q1  = s1 + 512;
    float* s2  = q1 + 512;
    float* q2  = s2 + 1024;
    float* sc1 = q2 + 1024;                  // written by k_finalize
    float* sh1 = sc1 + 512;
    unsigned long long* keys = (unsigned long long*)(ws + 32768);  // [30720] u64
    unsigned short* w1t = (unsigned short*)(ws + 32768 + 245760);  // [512][128]
    unsigned short* w2t = w1t + (size_t)512 * 128;                 // [1024][512]
    unsigned short* X   = w2t + (size_t)1024 * 512;                // [30720][128]
    unsigned short* Y1  = X   + (size_t)MROWS * 128;               // [30720][512]
    unsigned short* Y2  = Y1  + (size_t)MROWS * 512;               // [30720][1024]

    k_prep<<<264, 256, 0, stream>>>(W1, W2, w1t, w2t, s1, keys);
    k_scan<<<P_N * SPLIT, 256, 0, stream>>>(end_pos, rel_pos, bpts, keys);
    k_assemble<<<P_N, 256, 0, stream>>>(keys, end_pos, rel_pos, bpts, Wsp, bsp, h, X);
    k_gemm<128, true><<<(MROWS / 128) * (512 / 128), 256, 0, stream>>>(
        X, w1t, b1, Y1, MROWS, 512, s1, q1);
    k_finalize<<<2, 256, 0, stream>>>(s1, q1, g1, be1, sc1, sh1, 512);
    k_bnrelu<<<MROWS / 32, 256, 0, stream>>>(Y1, sc1, sh1);
    k_gemm<512, true><<<(MROWS / 128) * (1024 / 128), 256, 0, stream>>>(
        Y1, w2t, b2, Y2, MROWS, 1024, s2, q2);
    k_bnmax<<<(P_N * 128) / 256, 256, 0, stream>>>(Y2, s2, q2, g2, be2, out);
}

// Round 6
// 200.978 us; speedup vs baseline: 1.0635x; 1.0635x over previous
//
#include <hip/hip_runtime.h>
#include <hip/hip_bf16.h>
#include <math.h>

#define P_N   2048
#define B_N   10000
#define NB    15
#define MROWS (P_N * NB)   // 30720
#define SPLIT 5
#define BPB   (B_N / SPLIT)  // 2000 boundary points per scan block

typedef __bf16 bf16x8 __attribute__((ext_vector_type(8)));
typedef float  f32x4  __attribute__((ext_vector_type(4)));

__device__ __forceinline__ float bf2f(unsigned short u) {
    union { unsigned int i; float f; } v; v.i = ((unsigned int)u) << 16; return v.f;
}
__device__ __forceinline__ unsigned short f2bf(float f) {
    union { float f; unsigned int i; } v; v.f = f;
    unsigned int i = v.i;
    i += 0x7FFFu + ((i >> 16) & 1u);
    return (unsigned short)(i >> 16);
}
__device__ __forceinline__ void gld_lds16(const unsigned short* g, unsigned short* l) {
    __builtin_amdgcn_global_load_lds(
        (const __attribute__((address_space(1))) unsigned int*)g,
        (__attribute__((address_space(3))) unsigned int*)l, 16, 0, 0);
}

// ---- K0: tiled transpose W1/W2 -> bf16 [N][K]; zero stats; init keys --------
__global__ __launch_bounds__(256) void k_prep(const float* __restrict__ W1,
        const float* __restrict__ W2, unsigned short* __restrict__ w1t,
        unsigned short* __restrict__ w2t, float* __restrict__ stats,
        unsigned long long* __restrict__ keys) {
    int blk = blockIdx.x, tid = threadIdx.x;
    if (blk < 144) {
        __shared__ unsigned short t[64][65];
        const float* W; unsigned short* O; int NC, K, tr, tc;
        if (blk < 16) { W = W1; O = w1t; NC = 512; K = 128; tr = blk & 1; tc = blk >> 1; }
        else { int b = blk - 16; W = W2; O = w2t; NC = 1024; K = 512; tr = b & 7; tc = b >> 3; }
        int r0 = tr * 64, c0 = tc * 64;
        int cx = tid & 63, rg = tid >> 6;
#pragma unroll
        for (int i = 0; i < 16; ++i) {
            int r = rg * 16 + i;
            t[r][cx] = f2bf(W[(size_t)(r0 + r) * NC + c0 + cx]);
        }
        __syncthreads();
#pragma unroll
        for (int i = 0; i < 16; ++i) {
            int n = rg * 16 + i;
            O[(size_t)(c0 + n) * K + r0 + cx] = t[cx][n];
        }
    } else {
        int idx = (blk - 144) * 256 + tid;        // 120 blocks: 30720 keys
        if (idx < MROWS) keys[idx] = ~0ull;
        if (idx < 3072) stats[idx] = 0.0f;
    }
}

// ---- K1a: scan boundary points, per-bin min via packed u64 atomicMin --------
__global__ __launch_bounds__(256) void k_scan(
        const float* __restrict__ end_pos, const float* __restrict__ rel_pos,
        const float* __restrict__ bpts, unsigned long long* __restrict__ keys) {
    __shared__ unsigned long long s_key[NB];
    int tid = threadIdx.x;
    int p = blockIdx.x / SPLIT, part = blockIdx.x % SPLIT;
    if (tid < NB) s_key[tid] = ~0ull;
    __syncthreads();

    float ex = end_pos[2 * p], ey = end_pos[2 * p + 1];
    float rx = rel_pos[2 * p], ry = rel_pos[2 * p + 1];
    float rr = rx * rx + ry * ry;
    float c, s;
    if (rr > 0.0f) { float inv = 1.0f / sqrtf(rr); c = rx * inv; s = ry * inv; }
    else           { c = 1.0f; s = 0.0f; }

    const float T0 = -4.704630109f, T1 = -2.246036774f, T2 = -1.376381920f,
                T3 = -0.900404044f, T4 = -0.577350269f, T5 = -0.324919696f,
                T6 = -0.105104235f, T7 =  0.105104235f, T8 =  0.324919696f,
                T9 =  0.577350269f, T10 = 0.900404044f, T11 = 1.376381920f,
                T12 = 2.246036774f, T13 = 4.704630109f;

    const float2* bp2 = (const float2*)bpts;
    int bstart = part * BPB;
    for (int b = bstart + tid; b < bstart + BPB; b += 256) {
        float2 pt = bp2[b];
        float dx = pt.x - ex, dy = pt.y - ey;
        float xb = dx * c + dy * s;
        float yb = dy * c - dx * s;
        float r2 = xb * xb + yb * yb;
        bool v3 = yb > T7 * xb;
        float ta = v3 ? T11 : T3;
        bool v2 = yb > ta * xb;
        float tb = v3 ? (v2 ? T13 : T9) : (v2 ? T5 : T1);
        bool v1 = yb > tb * xb;
        float tc = v3 ? (v2 ? (v1 ? 3.0e38f : T12) : (v1 ? T10 : T8))
                      : (v2 ? (v1 ? T6 : T4)       : (v1 ? T2 : T0));
        bool v0 = yb > tc * xb;
        int bin = (v3 ? 8 : 0) + (v2 ? 4 : 0) + (v1 ? 2 : 0) + (v0 ? 1 : 0);
        if (xb > 0.0f) {
            unsigned long long key =
                ((unsigned long long)__float_as_uint(r2) << 32) | (unsigned int)b;
            atomicMin(&s_key[bin], key);
        }
    }
    __syncthreads();
    if (tid < NB) atomicMin(&keys[p * NB + tid], s_key[tid]);
}

// ---- K1b: choose point/fallback, build X = [emb(64) | h(64)] per (p,cell) ---
__global__ __launch_bounds__(256) void k_assemble(
        const unsigned long long* __restrict__ keys,
        const float* __restrict__ end_pos, const float* __restrict__ rel_pos,
        const float* __restrict__ bpts, const float* __restrict__ Wsp,
        const float* __restrict__ bsp, const float* __restrict__ h,
        unsigned short* __restrict__ X) {
    __shared__ float2 s_rel[NB];
    int p = blockIdx.x, tid = threadIdx.x;
    if (tid < NB) {
        float ex = end_pos[2 * p], ey = end_pos[2 * p + 1];
        unsigned long long key = keys[p * NB + tid];
        float r = sqrtf(__uint_as_float((unsigned int)(key >> 32)));
        float relx, rely;
        if (r <= 2.0f) {
            int b = (int)(key & 0xFFFFFFFFu);
            relx = bpts[2 * b] - ex; rely = bpts[2 * b + 1] - ey;
        } else {
            float rx = rel_pos[2 * p], ry = rel_pos[2 * p + 1];
            float rr = rx * rx + ry * ry;
            float c, s;
            if (rr > 0.0f) { float inv = 1.0f / sqrtf(rr); c = rx * inv; s = ry * inv; }
            else           { c = 1.0f; s = 0.0f; }
            float th = ((float)tid + 0.5f) * (float)(M_PI / 15.0) - (float)(M_PI / 2.0);
            float xc = 2.0f * cosf(th), yc = 2.0f * sinf(th);
            relx = xc * c - yc * s;
            rely = xc * s + yc * c;
        }
        s_rel[tid] = make_float2(relx, rely);
    }
    __syncthreads();
    if (tid < NB * 16) {
        int cell = tid >> 4, e0 = (tid & 15) * 8;
        float2 rel = s_rel[cell];
        unsigned short ubuf[8];
        if (e0 < 64) {
            float4 w0a = *(const float4*)(Wsp + e0),      w0b = *(const float4*)(Wsp + e0 + 4);
            float4 w1a = *(const float4*)(Wsp + 64 + e0), w1b = *(const float4*)(Wsp + 64 + e0 + 4);
            float4 bba = *(const float4*)(bsp + e0),      bbb = *(const float4*)(bsp + e0 + 4);
            float w0[8] = {w0a.x,w0a.y,w0a.z,w0a.w,w0b.x,w0b.y,w0b.z,w0b.w};
            float w1[8] = {w1a.x,w1a.y,w1a.z,w1a.w,w1b.x,w1b.y,w1b.z,w1b.w};
            float bb[8] = {bba.x,bba.y,bba.z,bba.w,bbb.x,bbb.y,bbb.z,bbb.w};
#pragma unroll
            for (int j = 0; j < 8; ++j)
                ubuf[j] = f2bf(rel.x * w0[j] + rel.y * w1[j] + bb[j]);
        } else {
            float4 ha = *(const float4*)(h + p * 64 + (e0 - 64));
            float4 hb = *(const float4*)(h + p * 64 + (e0 - 64) + 4);
            float hv[8] = {ha.x,ha.y,ha.z,ha.w,hb.x,hb.y,hb.z,hb.w};
#pragma unroll
            for (int j = 0; j < 8; ++j) ubuf[j] = f2bf(hv[j]);
        }
        *(uint4*)(X + ((size_t)p * NB + cell) * 128 + e0) = *(uint4*)ubuf;
    }
}

// ---- GEMM: 128x128 tile, BK=32, depth-3 counted-vmcnt pipeline (T3/T4),
//      bank-uniform [kseg][row][8] LDS chunks, LDS-staged C epilogue ----------
template<int K, bool STATS>
__global__ __launch_bounds__(256) void k_gemm(
        const unsigned short* __restrict__ A, const unsigned short* __restrict__ Bt,
        const float* __restrict__ bias, unsigned short* __restrict__ C,
        int M, int N, float* __restrict__ osum, float* __restrict__ osq) {
    __shared__ __align__(16) unsigned short lds[24576];  // 3 bufs × (A 8KB | B 8KB)
    int tid = threadIdx.x;
    int tiles_m = M >> 7;
    int bm = blockIdx.x % tiles_m, bn = blockIdx.x / tiles_m;
    int row0 = bm << 7, col0 = bn << 7;
    int lane = tid & 63, wave = tid >> 6;
    int wr = wave >> 1, wc = wave & 1;
    int frow = lane & 15, kq = lane >> 4;

    f32x4 zero = {0.f, 0.f, 0.f, 0.f};
    f32x4 acc[4][4];
#pragma unroll
    for (int i = 0; i < 4; ++i)
#pragma unroll
        for (int j = 0; j < 4; ++j) acc[i][j] = zero;

    // staging: lane -> (row = lane&15, kseg = lane>>4); wave w covers rows
    // [w*32, w*32+32) as two 16-row chunks; chunk layout [kseg][row][8].
    const unsigned short* gA  = A  + (size_t)(row0 + wave * 32 + frow) * K + kq * 8;
    const unsigned short* gB  = Bt + (size_t)(col0 + wave * 32 + frow) * K + kq * 8;
    const unsigned short* gA2 = gA + (size_t)16 * K;
    const unsigned short* gB2 = gB + (size_t)16 * K;

    constexpr int NT = K / 32;
    static_assert(NT >= 3, "pipeline depth 3 requires >=3 k-tiles");

    // 4 gload_lds per wave per tile
    auto issue = [&](int t) {
        unsigned short* d = lds + (t % 3) * 8192;
        int ko = t * 32;
        gld_lds16(gA + ko,  d + wave * 1024);
        gld_lds16(gA2 + ko, d + wave * 1024 + 512);
        gld_lds16(gB + ko,  d + 4096 + wave * 1024);
        gld_lds16(gB2 + ko, d + 4096 + wave * 1024 + 512);
    };

    issue(0); issue(1); issue(2);              // 12 loads in flight

#pragma unroll
    for (int t = 0; t < NT; ++t) {
        // tile t's 4 loads retired; up to 8 (tiles t+1,t+2) remain in flight
        if (t + 2 < NT)      asm volatile("s_waitcnt vmcnt(8)" ::: "memory");
        else if (t + 1 < NT) asm volatile("s_waitcnt vmcnt(4)" ::: "memory");
        else                 asm volatile("s_waitcnt vmcnt(0)" ::: "memory");
        __builtin_amdgcn_s_barrier();          // all waves: tile t fully in LDS
        asm volatile("" ::: "memory");

        const unsigned short* buf = lds + (t % 3) * 8192;
        bf16x8 af[4], bfv[4];
#pragma unroll
        for (int i = 0; i < 4; ++i) {
            af[i]  = *(const bf16x8*)&buf[(wr * 4 + i) * 512 + kq * 128 + frow * 8];
            bfv[i] = *(const bf16x8*)&buf[4096 + (wc * 4 + i) * 512 + kq * 128 + frow * 8];
        }
        asm volatile("s_waitcnt lgkmcnt(0)" ::: "memory");
        __builtin_amdgcn_sched_barrier(0);
        __builtin_amdgcn_s_barrier();          // all waves done reading buf[t%3]
        asm volatile("" ::: "memory");

        if (t + 3 < NT) issue(t + 3);          // refill freed buffer

#pragma unroll
        for (int i = 0; i < 4; ++i)
#pragma unroll
            for (int j = 0; j < 4; ++j)
                acc[i][j] = __builtin_amdgcn_mfma_f32_16x16x32_bf16(af[i], bfv[j], acc[i][j], 0, 0, 0);
    }

    // epilogue: two 64-row bands; stage f2bf(acc+bias) in LDS, store coalesced
    unsigned short* ldsC = lds;
    int rbase = (lane >> 4) << 2;
#pragma unroll
    for (int ci = 0; ci < 2; ++ci) {
        __syncthreads();
        if (wr == ci) {
#pragma unroll
            for (int j = 0; j < 4; ++j) {
                int col = col0 + wc * 64 + j * 16 + frow;
                float bv = bias[col];
                float csum = 0.f, csq = 0.f;
#pragma unroll
                for (int i = 0; i < 4; ++i) {
#pragma unroll
                    for (int r = 0; r < 4; ++r) {
                        float y = acc[i][j][r] + bv;
                        ldsC[(i * 16 + rbase + r) * 136 + wc * 64 + j * 16 + frow] = f2bf(y);
                        if (STATS) { csum += y; csq = fmaf(y, y, csq); }
                    }
                }
                if (STATS) {
                    csum += __shfl_xor(csum, 16); csum += __shfl_xor(csum, 32);
                    csq  += __shfl_xor(csq, 16);  csq  += __shfl_xor(csq, 32);
                    if (lane < 16) { atomicAdd(&osum[col], csum); atomicAdd(&osq[col], csq); }
                }
            }
        }
        __syncthreads();
#pragma unroll
        for (int it = 0; it < 4; ++it) {
            int t = it * 256 + tid;
            int brow = t >> 4, seg = t & 15;
            *(uint4*)(C + (size_t)(row0 + ci * 64 + brow) * N + col0 + seg * 8) =
                *(const uint4*)&ldsC[brow * 136 + seg * 8];
        }
    }
}

// ---- BN + ReLU, in place, column-resident streaming (N=512); inline coeffs --
__global__ __launch_bounds__(256) void k_bnrelu(unsigned short* __restrict__ Y,
        const float* __restrict__ s, const float* __restrict__ q,
        const float* __restrict__ g, const float* __restrict__ be) {
    int tid = threadIdx.x;
    int seg  = tid & 63;                 // 64 uint4 segments per 512-col row
    int roff = tid >> 6;                 // 4 row-phases
    int r0 = blockIdx.x * 32;
    int c0 = seg * 8;
    const float invN = 1.0f / (float)MROWS;
    float scv[8], shv[8];
#pragma unroll
    for (int j = 0; j < 8; ++j) {
        float m = s[c0 + j] * invN;
        float v = q[c0 + j] * invN - m * m;
        float k = g[c0 + j] * rsqrtf(v + 1e-5f);
        scv[j] = k; shv[j] = be[c0 + j] - m * k;
    }
    for (int r = r0 + roff; r < r0 + 32; r += 4) {
        unsigned short* p = Y + (size_t)r * 512 + c0;
        uint4 v = *(const uint4*)p;
        unsigned short* u = (unsigned short*)&v;
#pragma unroll
        for (int j = 0; j < 8; ++j) {
            float x = fmaf(bf2f(u[j]), scv[j], shv[j]);
            u[j] = f2bf(fmaxf(x, 0.0f));
        }
        *(uint4*)p = v;
    }
}

// ---- BN2 (inline coeffs) + ReLU + max over 15 cells -> out (f32) ------------
__global__ void k_bnmax(const unsigned short* __restrict__ Y2, const float* __restrict__ s2,
                        const float* __restrict__ q2, const float* __restrict__ g2,
                        const float* __restrict__ be2, float* __restrict__ out) {
    int idx = blockIdx.x * 256 + threadIdx.x;      // 2048*128 threads
    int p = idx >> 7, cb = idx & 127;
    int c0 = cb << 3;
    const float invN = 1.0f / (float)MROWS;
    float4 sa = *(const float4*)(s2 + c0),  sb = *(const float4*)(s2 + c0 + 4);
    float4 qa = *(const float4*)(q2 + c0),  qb = *(const float4*)(q2 + c0 + 4);
    float4 ga = *(const float4*)(g2 + c0),  gb = *(const float4*)(g2 + c0 + 4);
    float4 ea = *(const float4*)(be2 + c0), eb = *(const float4*)(be2 + c0 + 4);
    float sv[8] = {sa.x,sa.y,sa.z,sa.w,sb.x,sb.y,sb.z,sb.w};
    float qv[8] = {qa.x,qa.y,qa.z,qa.w,qb.x,qb.y,qb.z,qb.w};
    float gv[8] = {ga.x,ga.y,ga.z,ga.w,gb.x,gb.y,gb.z,gb.w};
    float ev[8] = {ea.x,ea.y,ea.z,ea.w,eb.x,eb.y,eb.z,eb.w};
    float scv[8], shv[8];
#pragma unroll
    for (int j = 0; j < 8; ++j) {
        float m = sv[j] * invN;
        float v = qv[j] * invN - m * m;
        float k = gv[j] * rsqrtf(v + 1e-5f);
        scv[j] = k; shv[j] = ev[j] - m * k;
    }
    float mx[8];
#pragma unroll
    for (int j = 0; j < 8; ++j) mx[j] = -3.0e38f;
#pragma unroll
    for (int cell = 0; cell < NB; ++cell) {
        uint4 v = *(const uint4*)(Y2 + ((size_t)(p * NB + cell)) * 1024 + c0);
        const unsigned short* u = (const unsigned short*)&v;
#pragma unroll
        for (int j = 0; j < 8; ++j) {
            float x = fmaf(bf2f(u[j]), scv[j], shv[j]);
            mx[j] = fmaxf(mx[j], x);
        }
    }
    float4 o0, o1;
    o0.x = fmaxf(mx[0], 0.f); o0.y = fmaxf(mx[1], 0.f);
    o0.z = fmaxf(mx[2], 0.f); o0.w = fmaxf(mx[3], 0.f);
    o1.x = fmaxf(mx[4], 0.f); o1.y = fmaxf(mx[5], 0.f);
    o1.z = fmaxf(mx[6], 0.f); o1.w = fmaxf(mx[7], 0.f);
    *(float4*)(out + (size_t)p * 1024 + c0)     = o0;
    *(float4*)(out + (size_t)p * 1024 + c0 + 4) = o1;
}

extern "C" void kernel_launch(void* const* d_in, const int* in_sizes, int n_in,
                              void* d_out, int out_size, void* d_ws, size_t ws_size,
                              hipStream_t stream) {
    const float* h       = (const float*)d_in[0];
    const float* end_pos = (const float*)d_in[1];
    const float* rel_pos = (const float*)d_in[2];
    const float* bpts    = (const float*)d_in[3];
    const float* Wsp     = (const float*)d_in[4];
    const float* bsp     = (const float*)d_in[5];
    const float* W1      = (const float*)d_in[6];
    const float* b1      = (const float*)d_in[7];
    const float* g1      = (const float*)d_in[8];
    const float* be1     = (const float*)d_in[9];
    const float* W2      = (const float*)d_in[10];
    const float* b2      = (const float*)d_in[11];
    const float* g2      = (const float*)d_in[12];
    const float* be2     = (const float*)d_in[13];
    float* out = (float*)d_out;

    char* ws = (char*)d_ws;
    float* s1  = (float*)ws;                 // zeroed by k_prep (first 3072 f32)
    float* q1  = s1 + 512;
    float* s2  = q1 + 512;
    float* q2  = s2 + 1024;
    unsigned long long* keys = (unsigned long long*)(ws + 32768);  // [30720] u64
    unsigned short* w1t = (unsigned short*)(ws + 32768 + 245760);  // [512][128]
    unsigned short* w2t = w1t + (size_t)512 * 128;                 // [1024][512]
    unsigned short* X   = w2t + (size_t)1024 * 512;                // [30720][128]
    unsigned short* Y1  = X   + (size_t)MROWS * 128;               // [30720][512]
    unsigned short* Y2  = Y1  + (size_t)MROWS * 512;               // [30720][1024]

    k_prep<<<264, 256, 0, stream>>>(W1, W2, w1t, w2t, s1, keys);
    k_scan<<<P_N * SPLIT, 256, 0, stream>>>(end_pos, rel_pos, bpts, keys);
    k_assemble<<<P_N, 256, 0, stream>>>(keys, end_pos, rel_pos, bpts, Wsp, bsp, h, X);
    k_gemm<128, true><<<(MROWS / 128) * (512 / 128), 256, 0, stream>>>(
        X, w1t, b1, Y1, MROWS, 512, s1, q1);
    k_bnrelu<<<MROWS / 32, 256, 0, stream>>>(Y1, s1, q1, g1, be1);
    k_gemm<512, true><<<(MROWS / 128) * (1024 / 128), 256, 0, stream>>>(
        Y1, w2t, b2, Y2, MROWS, 1024, s2, q2);
    k_bnmax<<<(P_N * 128) / 256, 256, 0, stream>>>(Y2, s2, q2, g2, be2, out);
}

// Round 7
// 186.474 us; speedup vs baseline: 1.1463x; 1.0778x over previous
//
#include <hip/hip_runtime.h>
#include <hip/hip_bf16.h>
#include <math.h>

#define P_N   2048
#define B_N   10000
#define NB    15
#define MROWS (P_N * NB)   // 30720
#define SPLIT 5
#define BPB   (B_N / SPLIT)  // 2000 boundary points per scan block

typedef __bf16 bf16x8 __attribute__((ext_vector_type(8)));
typedef float  f32x4  __attribute__((ext_vector_type(4)));

__device__ __forceinline__ float bf2f(unsigned short u) {
    union { unsigned int i; float f; } v; v.i = ((unsigned int)u) << 16; return v.f;
}
__device__ __forceinline__ unsigned short f2bf(float f) {
    union { float f; unsigned int i; } v; v.f = f;
    unsigned int i = v.i;
    i += 0x7FFFu + ((i >> 16) & 1u);
    return (unsigned short)(i >> 16);
}
__device__ __forceinline__ void gld_lds16(const unsigned short* g, unsigned short* l) {
    __builtin_amdgcn_global_load_lds(
        (const __attribute__((address_space(1))) unsigned int*)g,
        (__attribute__((address_space(3))) unsigned int*)l, 16, 0, 0);
}

// ---- K0: tiled transpose W1/W2 -> bf16 [N][K]; zero stats; init keys --------
__global__ __launch_bounds__(256) void k_prep(const float* __restrict__ W1,
        const float* __restrict__ W2, unsigned short* __restrict__ w1t,
        unsigned short* __restrict__ w2t, float* __restrict__ stats,
        unsigned long long* __restrict__ keys) {
    int blk = blockIdx.x, tid = threadIdx.x;
    if (blk < 144) {
        __shared__ unsigned short t[64][65];
        const float* W; unsigned short* O; int NC, K, tr, tc;
        if (blk < 16) { W = W1; O = w1t; NC = 512; K = 128; tr = blk & 1; tc = blk >> 1; }
        else { int b = blk - 16; W = W2; O = w2t; NC = 1024; K = 512; tr = b & 7; tc = b >> 3; }
        int r0 = tr * 64, c0 = tc * 64;
        int cx = tid & 63, rg = tid >> 6;
#pragma unroll
        for (int i = 0; i < 16; ++i) {
            int r = rg * 16 + i;
            t[r][cx] = f2bf(W[(size_t)(r0 + r) * NC + c0 + cx]);
        }
        __syncthreads();
#pragma unroll
        for (int i = 0; i < 16; ++i) {
            int n = rg * 16 + i;
            O[(size_t)(c0 + n) * K + r0 + cx] = t[cx][n];
        }
    } else {
        int idx = (blk - 144) * 256 + tid;        // 120 blocks: 30720 keys
        if (idx < MROWS) keys[idx] = ~0ull;
        if (idx < 3072) stats[idx] = 0.0f;
    }
}

// ---- K1a: scan boundary points, per-bin min via packed u64 atomicMin --------
__global__ __launch_bounds__(256) void k_scan(
        const float* __restrict__ end_pos, const float* __restrict__ rel_pos,
        const float* __restrict__ bpts, unsigned long long* __restrict__ keys) {
    __shared__ unsigned long long s_key[NB];
    int tid = threadIdx.x;
    int p = blockIdx.x / SPLIT, part = blockIdx.x % SPLIT;
    if (tid < NB) s_key[tid] = ~0ull;
    __syncthreads();

    float ex = end_pos[2 * p], ey = end_pos[2 * p + 1];
    float rx = rel_pos[2 * p], ry = rel_pos[2 * p + 1];
    float rr = rx * rx + ry * ry;
    float c, s;
    if (rr > 0.0f) { float inv = 1.0f / sqrtf(rr); c = rx * inv; s = ry * inv; }
    else           { c = 1.0f; s = 0.0f; }

    const float T0 = -4.704630109f, T1 = -2.246036774f, T2 = -1.376381920f,
                T3 = -0.900404044f, T4 = -0.577350269f, T5 = -0.324919696f,
                T6 = -0.105104235f, T7 =  0.105104235f, T8 =  0.324919696f,
                T9 =  0.577350269f, T10 = 0.900404044f, T11 = 1.376381920f,
                T12 = 2.246036774f, T13 = 4.704630109f;

    const float2* bp2 = (const float2*)bpts;
    int bstart = part * BPB;
    for (int b = bstart + tid; b < bstart + BPB; b += 256) {
        float2 pt = bp2[b];
        float dx = pt.x - ex, dy = pt.y - ey;
        float xb = dx * c + dy * s;
        float yb = dy * c - dx * s;
        float r2 = xb * xb + yb * yb;
        bool v3 = yb > T7 * xb;
        float ta = v3 ? T11 : T3;
        bool v2 = yb > ta * xb;
        float tb = v3 ? (v2 ? T13 : T9) : (v2 ? T5 : T1);
        bool v1 = yb > tb * xb;
        float tc = v3 ? (v2 ? (v1 ? 3.0e38f : T12) : (v1 ? T10 : T8))
                      : (v2 ? (v1 ? T6 : T4)       : (v1 ? T2 : T0));
        bool v0 = yb > tc * xb;
        int bin = (v3 ? 8 : 0) + (v2 ? 4 : 0) + (v1 ? 2 : 0) + (v0 ? 1 : 0);
        if (xb > 0.0f) {
            unsigned long long key =
                ((unsigned long long)__float_as_uint(r2) << 32) | (unsigned int)b;
            atomicMin(&s_key[bin], key);
        }
    }
    __syncthreads();
    if (tid < NB) atomicMin(&keys[p * NB + tid], s_key[tid]);
}

// ---- K1b: choose point/fallback, build X = [emb(64) | h(64)] per (p,cell) ---
__global__ __launch_bounds__(256) void k_assemble(
        const unsigned long long* __restrict__ keys,
        const float* __restrict__ end_pos, const float* __restrict__ rel_pos,
        const float* __restrict__ bpts, const float* __restrict__ Wsp,
        const float* __restrict__ bsp, const float* __restrict__ h,
        unsigned short* __restrict__ X) {
    __shared__ float2 s_rel[NB];
    int p = blockIdx.x, tid = threadIdx.x;
    if (tid < NB) {
        float ex = end_pos[2 * p], ey = end_pos[2 * p + 1];
        unsigned long long key = keys[p * NB + tid];
        float r = sqrtf(__uint_as_float((unsigned int)(key >> 32)));
        float relx, rely;
        if (r <= 2.0f) {
            int b = (int)(key & 0xFFFFFFFFu);
            relx = bpts[2 * b] - ex; rely = bpts[2 * b + 1] - ey;
        } else {
            float rx = rel_pos[2 * p], ry = rel_pos[2 * p + 1];
            float rr = rx * rx + ry * ry;
            float c, s;
            if (rr > 0.0f) { float inv = 1.0f / sqrtf(rr); c = rx * inv; s = ry * inv; }
            else           { c = 1.0f; s = 0.0f; }
            float th = ((float)tid + 0.5f) * (float)(M_PI / 15.0) - (float)(M_PI / 2.0);
            float xc = 2.0f * cosf(th), yc = 2.0f * sinf(th);
            relx = xc * c - yc * s;
            rely = xc * s + yc * c;
        }
        s_rel[tid] = make_float2(relx, rely);
    }
    __syncthreads();
    if (tid < NB * 16) {
        int cell = tid >> 4, e0 = (tid & 15) * 8;
        float2 rel = s_rel[cell];
        unsigned short ubuf[8];
        if (e0 < 64) {
            float4 w0a = *(const float4*)(Wsp + e0),      w0b = *(const float4*)(Wsp + e0 + 4);
            float4 w1a = *(const float4*)(Wsp + 64 + e0), w1b = *(const float4*)(Wsp + 64 + e0 + 4);
            float4 bba = *(const float4*)(bsp + e0),      bbb = *(const float4*)(bsp + e0 + 4);
            float w0[8] = {w0a.x,w0a.y,w0a.z,w0a.w,w0b.x,w0b.y,w0b.z,w0b.w};
            float w1[8] = {w1a.x,w1a.y,w1a.z,w1a.w,w1b.x,w1b.y,w1b.z,w1b.w};
            float bb[8] = {bba.x,bba.y,bba.z,bba.w,bbb.x,bbb.y,bbb.z,bbb.w};
#pragma unroll
            for (int j = 0; j < 8; ++j)
                ubuf[j] = f2bf(rel.x * w0[j] + rel.y * w1[j] + bb[j]);
        } else {
            float4 ha = *(const float4*)(h + p * 64 + (e0 - 64));
            float4 hb = *(const float4*)(h + p * 64 + (e0 - 64) + 4);
            float hv[8] = {ha.x,ha.y,ha.z,ha.w,hb.x,hb.y,hb.z,hb.w};
#pragma unroll
            for (int j = 0; j < 8; ++j) ubuf[j] = f2bf(hv[j]);
        }
        *(uint4*)(X + ((size_t)p * NB + cell) * 128 + e0) = *(uint4*)ubuf;
    }
}

// ---- GEMM: 128x128 tile, BK=64, single-barrier 2-phase (T3-minimum),
//      XCD-grouped dispatch (A-panel sharers land on one XCD's L2),
//      bank-uniform [kseg][row][8] LDS chunks, LDS-staged C epilogue ----------
template<int K, bool STATS>
__global__ __launch_bounds__(256) void k_gemm(
        const unsigned short* __restrict__ A, const unsigned short* __restrict__ Bt,
        const float* __restrict__ bias, unsigned short* __restrict__ C,
        int M, int N, float* __restrict__ osum, float* __restrict__ osq) {
    __shared__ __align__(16) unsigned short lds[32768];  // 2 bufs × 32KB (A16|B16)
    int tid = threadIdx.x;

    // dispatch remap: blocks sharing an A-panel (same bm, all bn) get indices
    // d ≡ bm (mod 8) -> same XCD -> A-panel stays in that XCD's L2.
    int nbt = N >> 7;
    int d = blockIdx.x;
    int m5 = d >> 3;
    int bn = m5 % nbt;
    int bm = (d & 7) + ((m5 / nbt) << 3);
    int row0 = bm << 7, col0 = bn << 7;

    int lane = tid & 63, wave = tid >> 6;
    int wr = wave >> 1, wc = wave & 1;
    int frow = lane & 15, kq = lane >> 4;

    f32x4 zero = {0.f, 0.f, 0.f, 0.f};
    f32x4 acc[4][4];
#pragma unroll
    for (int i = 0; i < 4; ++i)
#pragma unroll
        for (int j = 0; j < 4; ++j) acc[i][j] = zero;

    // staging: lane -> (row = lane&15, kseg = lane>>4); wave w covers rows
    // [w*32, w*32+32) as two 16-row chunks; chunk layout [kseg][row][8].
    // Buffer layout (elems): [buf(2)x16384][sub(2)x8192: A 0..4095 | B 4096..8191]
    const unsigned short* gA  = A  + (size_t)(row0 + wave * 32 + frow) * K + kq * 8;
    const unsigned short* gB  = Bt + (size_t)(col0 + wave * 32 + frow) * K + kq * 8;
    const unsigned short* gA2 = gA + (size_t)16 * K;
    const unsigned short* gB2 = gB + (size_t)16 * K;

    constexpr int NT2 = K / 64;
    static_assert(NT2 >= 2, "need >=2 K-tiles");

    auto issue = [&](int t) {      // 8 gload_lds per wave per BK=64 tile
        unsigned short* dst = lds + (t & 1) * 16384;
        int ko = t * 64;
        gld_lds16(gA  + ko,      dst + wave * 1024);
        gld_lds16(gA2 + ko,      dst + wave * 1024 + 512);
        gld_lds16(gB  + ko,      dst + 4096 + wave * 1024);
        gld_lds16(gB2 + ko,      dst + 4096 + wave * 1024 + 512);
        gld_lds16(gA  + ko + 32, dst + 8192 + wave * 1024);
        gld_lds16(gA2 + ko + 32, dst + 8192 + wave * 1024 + 512);
        gld_lds16(gB  + ko + 32, dst + 12288 + wave * 1024);
        gld_lds16(gB2 + ko + 32, dst + 12288 + wave * 1024 + 512);
    };

    issue(0);
    asm volatile("s_waitcnt vmcnt(0)" ::: "memory");
    __builtin_amdgcn_s_barrier();
    asm volatile("" ::: "memory");

#pragma unroll
    for (int t = 0; t < NT2; ++t) {
        if (t + 1 < NT2) issue(t + 1);         // loads fly during this tile's compute
        const unsigned short* buf = lds + (t & 1) * 16384;
#pragma unroll
        for (int s = 0; s < 2; ++s) {
            bf16x8 af[4], bfv[4];
#pragma unroll
            for (int i = 0; i < 4; ++i) {
                af[i]  = *(const bf16x8*)&buf[s * 8192 + (wr * 4 + i) * 512 + kq * 128 + frow * 8];
                bfv[i] = *(const bf16x8*)&buf[s * 8192 + 4096 + (wc * 4 + i) * 512 + kq * 128 + frow * 8];
            }
#pragma unroll
            for (int i = 0; i < 4; ++i)
#pragma unroll
                for (int j = 0; j < 4; ++j)
                    acc[i][j] = __builtin_amdgcn_mfma_f32_16x16x32_bf16(af[i], bfv[j], acc[i][j], 0, 0, 0);
        }
        asm volatile("s_waitcnt vmcnt(0)" ::: "memory");   // next tile landed
        __builtin_amdgcn_s_barrier();                       // + this tile's reads done
        asm volatile("" ::: "memory");
    }

    // epilogue: two 64-row bands; stage f2bf(acc+bias) in LDS, store coalesced
    unsigned short* ldsC = lds;
    int rbase = (lane >> 4) << 2;
#pragma unroll
    for (int ci = 0; ci < 2; ++ci) {
        __syncthreads();
        if (wr == ci) {
#pragma unroll
            for (int j = 0; j < 4; ++j) {
                int col = col0 + wc * 64 + j * 16 + frow;
                float bv = bias[col];
                float csum = 0.f, csq = 0.f;
#pragma unroll
                for (int i = 0; i < 4; ++i) {
#pragma unroll
                    for (int r = 0; r < 4; ++r) {
                        float y = acc[i][j][r] + bv;
                        ldsC[(i * 16 + rbase + r) * 136 + wc * 64 + j * 16 + frow] = f2bf(y);
                        if (STATS) { csum += y; csq = fmaf(y, y, csq); }
                    }
                }
                if (STATS) {
                    csum += __shfl_xor(csum, 16); csum += __shfl_xor(csum, 32);
                    csq  += __shfl_xor(csq, 16);  csq  += __shfl_xor(csq, 32);
                    if (lane < 16) { atomicAdd(&osum[col], csum); atomicAdd(&osq[col], csq); }
                }
            }
        }
        __syncthreads();
#pragma unroll
        for (int it = 0; it < 4; ++it) {
            int t = it * 256 + tid;
            int brow = t >> 4, seg = t & 15;
            *(uint4*)(C + (size_t)(row0 + ci * 64 + brow) * N + col0 + seg * 8) =
                *(const uint4*)&ldsC[brow * 136 + seg * 8];
        }
    }
}

// ---- BN + ReLU, in place, column-resident streaming (N=512); inline coeffs --
__global__ __launch_bounds__(256) void k_bnrelu(unsigned short* __restrict__ Y,
        const float* __restrict__ s, const float* __restrict__ q,
        const float* __restrict__ g, const float* __restrict__ be) {
    int tid = threadIdx.x;
    int seg  = tid & 63;                 // 64 uint4 segments per 512-col row
    int roff = tid >> 6;                 // 4 row-phases
    int r0 = blockIdx.x * 32;
    int c0 = seg * 8;
    const float invN = 1.0f / (float)MROWS;
    float scv[8], shv[8];
#pragma unroll
    for (int j = 0; j < 8; ++j) {
        float m = s[c0 + j] * invN;
        float v = q[c0 + j] * invN - m * m;
        float k = g[c0 + j] * rsqrtf(v + 1e-5f);
        scv[j] = k; shv[j] = be[c0 + j] - m * k;
    }
    for (int r = r0 + roff; r < r0 + 32; r += 4) {
        unsigned short* p = Y + (size_t)r * 512 + c0;
        uint4 v = *(const uint4*)p;
        unsigned short* u = (unsigned short*)&v;
#pragma unroll
        for (int j = 0; j < 8; ++j) {
            float x = fmaf(bf2f(u[j]), scv[j], shv[j]);
            u[j] = f2bf(fmaxf(x, 0.0f));
        }
        *(uint4*)p = v;
    }
}

// ---- BN2 (inline coeffs) + ReLU + max over 15 cells -> out (f32) ------------
__global__ void k_bnmax(const unsigned short* __restrict__ Y2, const float* __restrict__ s2,
                        const float* __restrict__ q2, const float* __restrict__ g2,
                        const float* __restrict__ be2, float* __restrict__ out) {
    int idx = blockIdx.x * 256 + threadIdx.x;      // 2048*128 threads
    int p = idx >> 7, cb = idx & 127;
    int c0 = cb << 3;
    const float invN = 1.0f / (float)MROWS;
    float4 sa = *(const float4*)(s2 + c0),  sb = *(const float4*)(s2 + c0 + 4);
    float4 qa = *(const float4*)(q2 + c0),  qb = *(const float4*)(q2 + c0 + 4);
    float4 ga = *(const float4*)(g2 + c0),  gb = *(const float4*)(g2 + c0 + 4);
    float4 ea = *(const float4*)(be2 + c0), eb = *(const float4*)(be2 + c0 + 4);
    float sv[8] = {sa.x,sa.y,sa.z,sa.w,sb.x,sb.y,sb.z,sb.w};
    float qv[8] = {qa.x,qa.y,qa.z,qa.w,qb.x,qb.y,qb.z,qb.w};
    float gv[8] = {ga.x,ga.y,ga.z,ga.w,gb.x,gb.y,gb.z,gb.w};
    float ev[8] = {ea.x,ea.y,ea.z,ea.w,eb.x,eb.y,eb.z,eb.w};
    float scv[8], shv[8];
#pragma unroll
    for (int j = 0; j < 8; ++j) {
        float m = sv[j] * invN;
        float v = qv[j] * invN - m * m;
        float k = gv[j] * rsqrtf(v + 1e-5f);
        scv[j] = k; shv[j] = ev[j] - m * k;
    }
    float mx[8];
#pragma unroll
    for (int j = 0; j < 8; ++j) mx[j] = -3.0e38f;
#pragma unroll
    for (int cell = 0; cell < NB; ++cell) {
        uint4 v = *(const uint4*)(Y2 + ((size_t)(p * NB + cell)) * 1024 + c0);
        const unsigned short* u = (const unsigned short*)&v;
#pragma unroll
        for (int j = 0; j < 8; ++j) {
            float x = fmaf(bf2f(u[j]), scv[j], shv[j]);
            mx[j] = fmaxf(mx[j], x);
        }
    }
    float4 o0, o1;
    o0.x = fmaxf(mx[0], 0.f); o0.y = fmaxf(mx[1], 0.f);
    o0.z = fmaxf(mx[2], 0.f); o0.w = fmaxf(mx[3], 0.f);
    o1.x = fmaxf(mx[4], 0.f); o1.y = fmaxf(mx[5], 0.f);
    o1.z = fmaxf(mx[6], 0.f); o1.w = fmaxf(mx[7], 0.f);
    *(float4*)(out + (size_t)p * 1024 + c0)     = o0;
    *(float4*)(out + (size_t)p * 1024 + c0 + 4) = o1;
}

extern "C" void kernel_launch(void* const* d_in, const int* in_sizes, int n_in,
                              void* d_out, int out_size, void* d_ws, size_t ws_size,
                              hipStream_t stream) {
    const float* h       = (const float*)d_in[0];
    const float* end_pos = (const float*)d_in[1];
    const float* rel_pos = (const float*)d_in[2];
    const float* bpts    = (const float*)d_in[3];
    const float* Wsp     = (const float*)d_in[4];
    const float* bsp     = (const float*)d_in[5];
    const float* W1      = (const float*)d_in[6];
    const float* b1      = (const float*)d_in[7];
    const float* g1      = (const float*)d_in[8];
    const float* be1     = (const float*)d_in[9];
    const float* W2      = (const float*)d_in[10];
    const float* b2      = (const float*)d_in[11];
    const float* g2      = (const float*)d_in[12];
    const float* be2     = (const float*)d_in[13];
    float* out = (float*)d_out;

    char* ws = (char*)d_ws;
    float* s1  = (float*)ws;                 // zeroed by k_prep (first 3072 f32)
    float* q1  = s1 + 512;
    float* s2  = q1 + 512;
    float* q2  = s2 + 1024;
    unsigned long long* keys = (unsigned long long*)(ws + 32768);  // [30720] u64
    unsigned short* w1t = (unsigned short*)(ws + 32768 + 245760);  // [512][128]
    unsigned short* w2t = w1t + (size_t)512 * 128;                 // [1024][512]
    unsigned short* X   = w2t + (size_t)1024 * 512;                // [30720][128]
    unsigned short* Y1  = X   + (size_t)MROWS * 128;               // [30720][512]
    unsigned short* Y2  = Y1  + (size_t)MROWS * 512;               // [30720][1024]

    k_prep<<<264, 256, 0, stream>>>(W1, W2, w1t, w2t, s1, keys);
    k_scan<<<P_N * SPLIT, 256, 0, stream>>>(end_pos, rel_pos, bpts, keys);
    k_assemble<<<P_N, 256, 0, stream>>>(keys, end_pos, rel_pos, bpts, Wsp, bsp, h, X);
    k_gemm<128, true><<<(MROWS / 128) * (512 / 128), 256, 0, stream>>>(
        X, w1t, b1, Y1, MROWS, 512, s1, q1);
    k_bnrelu<<<MROWS / 32, 256, 0, stream>>>(Y1, s1, q1, g1, be1);
    k_gemm<512, true><<<(MROWS / 128) * (1024 / 128), 256, 0, stream>>>(
        Y1, w2t, b2, Y2, MROWS, 1024, s2, q2);
    k_bnmax<<<(P_N * 128) / 256, 256, 0, stream>>>(Y2, s2, q2, g2, be2, out);
}

// Round 9
// 155.996 us; speedup vs baseline: 1.3702x; 1.1954x over previous
//
#include <hip/hip_runtime.h>
#include <hip/hip_bf16.h>
#include <math.h>

#define P_N   2048
#define B_N   10000
#define NB    15
#define MROWS (P_N * NB)   // 30720
#define SPLIT 5
#define BPB   (B_N / SPLIT)  // 2000 boundary points per scan block

typedef __bf16 bf16x8 __attribute__((ext_vector_type(8)));
typedef float  f32x4  __attribute__((ext_vector_type(4)));

__device__ __forceinline__ float bf2f(unsigned short u) {
    union { unsigned int i; float f; } v; v.i = ((unsigned int)u) << 16; return v.f;
}
__device__ __forceinline__ unsigned short f2bf(float f) {
    union { float f; unsigned int i; } v; v.f = f;
    unsigned int i = v.i;
    i += 0x7FFFu + ((i >> 16) & 1u);
    return (unsigned short)(i >> 16);
}
__device__ __forceinline__ void gld_lds16(const unsigned short* g, unsigned short* l) {
    __builtin_amdgcn_global_load_lds(
        (const __attribute__((address_space(1))) unsigned int*)g,
        (__attribute__((address_space(3))) unsigned int*)l, 16, 0, 0);
}
// monotone u32 key for f32 (x<y iff key(x)<key(y)); all real keys > 0
__device__ __forceinline__ unsigned fkey(float f) {
    unsigned b = __float_as_uint(f);
    return (b & 0x80000000u) ? ~b : (b | 0x80000000u);
}
__device__ __forceinline__ float funkey(unsigned key) {
    unsigned b = (key & 0x80000000u) ? (key ^ 0x80000000u) : ~key;
    return __uint_as_float(b);
}

// ---- K0: tiled transpose W1/W2 -> bf16 [N][K]; zero stats/keys/maxkeys ------
__global__ __launch_bounds__(256) void k_prep(const float* __restrict__ W1,
        const float* __restrict__ W2, unsigned short* __restrict__ w1t,
        unsigned short* __restrict__ w2t, float* __restrict__ stats,
        unsigned long long* __restrict__ keys, unsigned int* __restrict__ mkey) {
    int blk = blockIdx.x, tid = threadIdx.x;
    if (blk < 144) {
        __shared__ unsigned short t[64][65];
        const float* W; unsigned short* O; int NC, K, tr, tc;
        if (blk < 16) { W = W1; O = w1t; NC = 512; K = 128; tr = blk & 1; tc = blk >> 1; }
        else { int b = blk - 16; W = W2; O = w2t; NC = 1024; K = 512; tr = b & 7; tc = b >> 3; }
        int r0 = tr * 64, c0 = tc * 64;
        int cx = tid & 63, rg = tid >> 6;
#pragma unroll
        for (int i = 0; i < 16; ++i) {
            int r = rg * 16 + i;
            t[r][cx] = f2bf(W[(size_t)(r0 + r) * NC + c0 + cx]);
        }
        __syncthreads();
#pragma unroll
        for (int i = 0; i < 16; ++i) {
            int n = rg * 16 + i;
            O[(size_t)(c0 + n) * K + r0 + cx] = t[cx][n];
        }
    } else {
        int idx = (blk - 144) * 256 + tid;        // 8192 blocks: 2M mkey + misc
        if (idx < P_N * 1024) mkey[idx] = 0u;     // 0 < fkey(any real)
        if (idx < MROWS) keys[idx] = ~0ull;
        if (idx < 3072) stats[idx] = 0.0f;
    }
}

// ---- K1a: scan boundary points, per-bin min via packed u64 atomicMin --------
__global__ __launch_bounds__(256) void k_scan(
        const float* __restrict__ end_pos, const float* __restrict__ rel_pos,
        const float* __restrict__ bpts, unsigned long long* __restrict__ keys) {
    __shared__ unsigned long long s_key[NB];
    int tid = threadIdx.x;
    int p = blockIdx.x / SPLIT, part = blockIdx.x % SPLIT;
    if (tid < NB) s_key[tid] = ~0ull;
    __syncthreads();

    float ex = end_pos[2 * p], ey = end_pos[2 * p + 1];
    float rx = rel_pos[2 * p], ry = rel_pos[2 * p + 1];
    float rr = rx * rx + ry * ry;
    float c, s;
    if (rr > 0.0f) { float inv = 1.0f / sqrtf(rr); c = rx * inv; s = ry * inv; }
    else           { c = 1.0f; s = 0.0f; }

    const float T0 = -4.704630109f, T1 = -2.246036774f, T2 = -1.376381920f,
                T3 = -0.900404044f, T4 = -0.577350269f, T5 = -0.324919696f,
                T6 = -0.105104235f, T7 =  0.105104235f, T8 =  0.324919696f,
                T9 =  0.577350269f, T10 = 0.900404044f, T11 = 1.376381920f,
                T12 = 2.246036774f, T13 = 4.704630109f;

    const float2* bp2 = (const float2*)bpts;
    int bstart = part * BPB;
    for (int b = bstart + tid; b < bstart + BPB; b += 256) {
        float2 pt = bp2[b];
        float dx = pt.x - ex, dy = pt.y - ey;
        float xb = dx * c + dy * s;
        float yb = dy * c - dx * s;
        float r2 = xb * xb + yb * yb;
        bool v3 = yb > T7 * xb;
        float ta = v3 ? T11 : T3;
        bool v2 = yb > ta * xb;
        float tb = v3 ? (v2 ? T13 : T9) : (v2 ? T5 : T1);
        bool v1 = yb > tb * xb;
        float tc = v3 ? (v2 ? (v1 ? 3.0e38f : T12) : (v1 ? T10 : T8))
                      : (v2 ? (v1 ? T6 : T4)       : (v1 ? T2 : T0));
        bool v0 = yb > tc * xb;
        int bin = (v3 ? 8 : 0) + (v2 ? 4 : 0) + (v1 ? 2 : 0) + (v0 ? 1 : 0);
        if (xb > 0.0f) {
            unsigned long long key =
                ((unsigned long long)__float_as_uint(r2) << 32) | (unsigned int)b;
            atomicMin(&s_key[bin], key);
        }
    }
    __syncthreads();
    if (tid < NB) atomicMin(&keys[p * NB + tid], s_key[tid]);
}

// ---- K1b: choose point/fallback, build X = [emb(64) | h(64)] per (p,cell) ---
__global__ __launch_bounds__(256) void k_assemble(
        const unsigned long long* __restrict__ keys,
        const float* __restrict__ end_pos, const float* __restrict__ rel_pos,
        const float* __restrict__ bpts, const float* __restrict__ Wsp,
        const float* __restrict__ bsp, const float* __restrict__ h,
        unsigned short* __restrict__ X) {
    __shared__ float2 s_rel[NB];
    int p = blockIdx.x, tid = threadIdx.x;
    if (tid < NB) {
        float ex = end_pos[2 * p], ey = end_pos[2 * p + 1];
        unsigned long long key = keys[p * NB + tid];
        float r = sqrtf(__uint_as_float((unsigned int)(key >> 32)));
        float relx, rely;
        if (r <= 2.0f) {
            int b = (int)(key & 0xFFFFFFFFu);
            relx = bpts[2 * b] - ex; rely = bpts[2 * b + 1] - ey;
        } else {
            float rx = rel_pos[2 * p], ry = rel_pos[2 * p + 1];
            float rr = rx * rx + ry * ry;
            float c, s;
            if (rr > 0.0f) { float inv = 1.0f / sqrtf(rr); c = rx * inv; s = ry * inv; }
            else           { c = 1.0f; s = 0.0f; }
            float th = ((float)tid + 0.5f) * (float)(M_PI / 15.0) - (float)(M_PI / 2.0);
            float xc = 2.0f * cosf(th), yc = 2.0f * sinf(th);
            relx = xc * c - yc * s;
            rely = xc * s + yc * c;
        }
        s_rel[tid] = make_float2(relx, rely);
    }
    __syncthreads();
    if (tid < NB * 16) {
        int cell = tid >> 4, e0 = (tid & 15) * 8;
        float2 rel = s_rel[cell];
        unsigned short ubuf[8];
        if (e0 < 64) {
            float4 w0a = *(const float4*)(Wsp + e0),      w0b = *(const float4*)(Wsp + e0 + 4);
            float4 w1a = *(const float4*)(Wsp + 64 + e0), w1b = *(const float4*)(Wsp + 64 + e0 + 4);
            float4 bba = *(const float4*)(bsp + e0),      bbb = *(const float4*)(bsp + e0 + 4);
            float w0[8] = {w0a.x,w0a.y,w0a.z,w0a.w,w0b.x,w0b.y,w0b.z,w0b.w};
            float w1[8] = {w1a.x,w1a.y,w1a.z,w1a.w,w1b.x,w1b.y,w1b.z,w1b.w};
            float bb[8] = {bba.x,bba.y,bba.z,bba.w,bbb.x,bbb.y,bbb.z,bbb.w};
#pragma unroll
            for (int j = 0; j < 8; ++j)
                ubuf[j] = f2bf(rel.x * w0[j] + rel.y * w1[j] + bb[j]);
        } else {
            float4 ha = *(const float4*)(h + p * 64 + (e0 - 64));
            float4 hb = *(const float4*)(h + p * 64 + (e0 - 64) + 4);
            float hv[8] = {ha.x,ha.y,ha.z,ha.w,hb.x,hb.y,hb.z,hb.w};
#pragma unroll
            for (int j = 0; j < 8; ++j) ubuf[j] = f2bf(hv[j]);
        }
        *(uint4*)(X + ((size_t)p * NB + cell) * 128 + e0) = *(uint4*)ubuf;
    }
}

// ---- 256x256 GEMM, BK=32, 8 waves (2Mx4N), 2-buf single-barrier pipeline ----
// WRITE_C: LDS-staged coalesced bf16 C write (GEMM1).
// !WRITE_C: no C store; band-staged per-ped max -> one atomicMax per
//           (ped,col)-segment (valid: BN2 sc>0 since g2=ones, ReLU monotone;
//           max over bf16-rounded y, identical to the R6 Y2 path).
// Both: fused column stats (sum, sumsq of y = acc + bias, f32).
template<int K, bool WRITE_C>
__global__ __launch_bounds__(512) void k_gemm256(
        const unsigned short* __restrict__ A, const unsigned short* __restrict__ Bt,
        const float* __restrict__ bias, unsigned short* __restrict__ C,
        int N, float* __restrict__ osum, float* __restrict__ osq,
        unsigned int* __restrict__ mkey) {
    __shared__ __align__(16) unsigned short lds[32768];  // 2 bufs x 16384 (A|B)
    int tid = threadIdx.x;

    // XCD-grouped remap: blocks sharing an A-panel sit on one XCD's L2
    int nbt = N >> 8;
    int d = blockIdx.x;
    int m5 = d >> 3;
    int bn = m5 % nbt;
    int bm = (d & 7) + ((m5 / nbt) << 3);
    int row0 = bm << 8, col0 = bn << 8;

    int lane = tid & 63, wave = tid >> 6;
    int wr = wave >> 2, wc = wave & 3;
    int frow = lane & 15, kq = lane >> 4;

    f32x4 zero = {0.f, 0.f, 0.f, 0.f};
    f32x4 acc[8][4];
#pragma unroll
    for (int i = 0; i < 8; ++i)
#pragma unroll
        for (int j = 0; j < 4; ++j) acc[i][j] = zero;

    // staging: waves 0-3 stage A rows [w*64, w*64+64), waves 4-7 stage B rows.
    // chunk = 16 rows x 32 k in [kseg][row][8] (1KB, linear in lane order).
    const unsigned short* gsrc =
        (wave < 4) ? (A  + (size_t)(row0 + (wave << 6) + frow) * K + kq * 8)
                   : (Bt + (size_t)(col0 + ((wave - 4) << 6) + frow) * K + kq * 8);
    unsigned ldsbase = (unsigned)wave * 2048;   // waves 4-7 land in B region 8192+

    auto issue = [&](int t) {      // 4 gload_lds per wave per BK=32 tile
        unsigned short* dst = lds + (t & 1) * 16384 + ldsbase;
        int ko = t * 32;
        gld_lds16(gsrc + ko,                    dst);
        gld_lds16(gsrc + ko + (size_t)16 * K,   dst + 512);
        gld_lds16(gsrc + ko + (size_t)32 * K,   dst + 1024);
        gld_lds16(gsrc + ko + (size_t)48 * K,   dst + 1536);
    };

    constexpr int NT = K / 32;
    issue(0);
    asm volatile("s_waitcnt vmcnt(0)" ::: "memory");
    __builtin_amdgcn_s_barrier();
    asm volatile("" ::: "memory");

#pragma unroll
    for (int t = 0; t < NT; ++t) {
        if (t + 1 < NT) issue(t + 1);          // loads fly under this tile's compute
        const unsigned short* buf = lds + (t & 1) * 16384;
        bf16x8 af[8], bfv[4];
#pragma unroll
        for (int i = 0; i < 8; ++i)
            af[i] = *(const bf16x8*)&buf[(wr * 8 + i) * 512 + kq * 128 + frow * 8];
#pragma unroll
        for (int j = 0; j < 4; ++j)
            bfv[j] = *(const bf16x8*)&buf[8192 + (wc * 4 + j) * 512 + kq * 128 + frow * 8];
#pragma unroll
        for (int i = 0; i < 8; ++i)
#pragma unroll
            for (int j = 0; j < 4; ++j)
                acc[i][j] = __builtin_amdgcn_mfma_f32_16x16x32_bf16(af[i], bfv[j], acc[i][j], 0, 0, 0);
        asm volatile("s_waitcnt vmcnt(0)" ::: "memory");   // next tile landed
        __builtin_amdgcn_s_barrier();                       // all reads of buf done
        asm volatile("" ::: "memory");
    }

    // ---- fused column stats (f32, pre-rounding) ----
    float bv[4];
#pragma unroll
    for (int j = 0; j < 4; ++j) bv[j] = bias[col0 + wc * 64 + j * 16 + frow];

#pragma unroll
    for (int j = 0; j < 4; ++j) {
        int col = col0 + wc * 64 + j * 16 + frow;
        float csum = 0.f, csq = 0.f;
#pragma unroll
        for (int i = 0; i < 8; ++i) {
#pragma unroll
            for (int r = 0; r < 4; ++r) {
                float y = acc[i][j][r] + bv[j];
                csum += y; csq = fmaf(y, y, csq);
            }
        }
        csum += __shfl_xor(csum, 16); csum += __shfl_xor(csum, 32);
        csq  += __shfl_xor(csq, 16);  csq  += __shfl_xor(csq, 32);
        if (lane < 16) { atomicAdd(&osum[col], csum); atomicAdd(&osq[col], csq); }
    }

    // ---- 4 bands of 64 rows: stage bf16(y) in LDS [64][264], then either
    //      coalesced C store (GEMM1) or per-ped max scan (GEMM2) ----
    unsigned short* ldsC = lds;     // 64*264 elems = 33 KB, main loop done
#pragma unroll
    for (int b = 0; b < 4; ++b) {
        __syncthreads();
        if (wr == (b >> 1)) {
#pragma unroll
            for (int j = 0; j < 4; ++j) {
#pragma unroll
                for (int ii = 0; ii < 4; ++ii) {
                    int i = (b & 1) * 4 + ii;
#pragma unroll
                    for (int r = 0; r < 4; ++r) {
                        float y = acc[i][j][r] + bv[j];
                        ldsC[(ii * 16 + kq * 4 + r) * 264 + wc * 64 + j * 16 + frow] = f2bf(y);
                    }
                }
            }
        }
        __syncthreads();
        if (WRITE_C) {
#pragma unroll
            for (int it = 0; it < 4; ++it) {
                int s = it * 512 + tid;          // 2048 uint4 = 64 rows x 256 cols
                int brow = s >> 5, seg = s & 31;
                *(uint4*)(C + (size_t)(row0 + b * 64 + brow) * N + col0 + seg * 8) =
                    *(const uint4*)&ldsC[brow * 264 + seg * 8];
            }
        } else {
            int col = tid & 255, half = tid >> 8;  // 2 threads per column
            int lrow0 = half * 32;
            int grow = row0 + b * 64 + lrow0;
            int curp = grow / 15;
            int rem = 15 - (grow - curp * 15);     // rows until ped boundary
            float mx = -3.0e38f;
#pragma unroll
            for (int r = 0; r < 32; ++r) {
                mx = fmaxf(mx, bf2f(ldsC[(lrow0 + r) * 264 + col]));
                if (--rem == 0) {
                    atomicMax(&mkey[(size_t)curp * 1024 + col0 + col], fkey(mx));
                    mx = -3.0e38f; ++curp; rem = 15;
                }
            }
            if (rem != 15)
                atomicMax(&mkey[(size_t)curp * 1024 + col0 + col], fkey(mx));
        }
    }
}

// ---- BN + ReLU, in place, column-resident streaming (N=512); inline coeffs --
__global__ __launch_bounds__(256) void k_bnrelu(unsigned short* __restrict__ Y,
        const float* __restrict__ s, const float* __restrict__ q,
        const float* __restrict__ g, const float* __restrict__ be) {
    int tid = threadIdx.x;
    int seg  = tid & 63;                 // 64 uint4 segments per 512-col row
    int roff = tid >> 6;                 // 4 row-phases
    int r0 = blockIdx.x * 32;
    int c0 = seg * 8;
    const float invN = 1.0f / (float)MROWS;
    float scv[8], shv[8];
#pragma unroll
    for (int j = 0; j < 8; ++j) {
        float m = s[c0 + j] * invN;
        float v = q[c0 + j] * invN - m * m;
        float k = g[c0 + j] * rsqrtf(v + 1e-5f);
        scv[j] = k; shv[j] = be[c0 + j] - m * k;
    }
    for (int r = r0 + roff; r < r0 + 32; r += 4) {
        unsigned short* p = Y + (size_t)r * 512 + c0;
        uint4 v = *(const uint4*)p;
        unsigned short* u = (unsigned short*)&v;
#pragma unroll
        for (int j = 0; j < 8; ++j) {
            float x = fmaf(bf2f(u[j]), scv[j], shv[j]);
            u[j] = f2bf(fmaxf(x, 0.0f));
        }
        *(uint4*)p = v;
    }
}

// ---- finalize: out = relu(sc2 * max_y + sh2) from u32-keyed maxima ----------
__global__ void k_bnfin(const unsigned int* __restrict__ mkey, const float* __restrict__ s2,
                        const float* __restrict__ q2, const float* __restrict__ g2,
                        const float* __restrict__ be2, float* __restrict__ out) {
    int idx = blockIdx.x * 256 + threadIdx.x;      // 2048*128 threads
    int p = idx >> 7, cb = idx & 127;
    int c0 = cb << 3;
    const float invN = 1.0f / (float)MROWS;
    float4 sa = *(const float4*)(s2 + c0),  sb = *(const float4*)(s2 + c0 + 4);
    float4 qa = *(const float4*)(q2 + c0),  qb = *(const float4*)(q2 + c0 + 4);
    float4 ga = *(const float4*)(g2 + c0),  gb = *(const float4*)(g2 + c0 + 4);
    float4 ea = *(const float4*)(be2 + c0), eb = *(const float4*)(be2 + c0 + 4);
    float sv[8] = {sa.x,sa.y,sa.z,sa.w,sb.x,sb.y,sb.z,sb.w};
    float qv[8] = {qa.x,qa.y,qa.z,qa.w,qb.x,qb.y,qb.z,qb.w};
    float gv[8] = {ga.x,ga.y,ga.z,ga.w,gb.x,gb.y,gb.z,gb.w};
    float ev[8] = {ea.x,ea.y,ea.z,ea.w,eb.x,eb.y,eb.z,eb.w};
    uint4 k0 = *(const uint4*)(mkey + (size_t)p * 1024 + c0);
    uint4 k1 = *(const uint4*)(mkey + (size_t)p * 1024 + c0 + 4);
    unsigned kv[8] = {k0.x,k0.y,k0.z,k0.w,k1.x,k1.y,k1.z,k1.w};
    float o[8];
#pragma unroll
    for (int j = 0; j < 8; ++j) {
        float m = sv[j] * invN;
        float v = qv[j] * invN - m * m;
        float k = gv[j] * rsqrtf(v + 1e-5f);
        float sh = ev[j] - m * k;
        o[j] = fmaxf(fmaf(funkey(kv[j]), k, sh), 0.0f);
    }
    float4 o0 = {o[0], o[1], o[2], o[3]};
    float4 o1 = {o[4], o[5], o[6], o[7]};
    *(float4*)(out + (size_t)p * 1024 + c0)     = o0;
    *(float4*)(out + (size_t)p * 1024 + c0 + 4) = o1;
}

extern "C" void kernel_launch(void* const* d_in, const int* in_sizes, int n_in,
                              void* d_out, int out_size, void* d_ws, size_t ws_size,
                              hipStream_t stream) {
    const float* h       = (const float*)d_in[0];
    const float* end_pos = (const float*)d_in[1];
    const float* rel_pos = (const float*)d_in[2];
    const float* bpts    = (const float*)d_in[3];
    const float* Wsp     = (const float*)d_in[4];
    const float* bsp     = (const float*)d_in[5];
    const float* W1      = (const float*)d_in[6];
    const float* b1      = (const float*)d_in[7];
    const float* g1      = (const float*)d_in[8];
    const float* be1     = (const float*)d_in[9];
    const float* W2      = (const float*)d_in[10];
    const float* b2      = (const float*)d_in[11];
    const float* g2      = (const float*)d_in[12];
    const float* be2     = (const float*)d_in[13];
    float* out = (float*)d_out;

    char* ws = (char*)d_ws;
    float* s1  = (float*)ws;                 // 3072 f32 zeroed by k_prep
    float* q1  = s1 + 512;
    float* s2  = q1 + 512;
    float* q2  = s2 + 1024;
    unsigned long long* keys = (unsigned long long*)(ws + 32768);      // [30720] u64
    unsigned int* mkey = (unsigned int*)(ws + 32768 + 245760);         // [2048*1024] u32
    unsigned short* w1t = (unsigned short*)(ws + 32768 + 245760 + 8388608); // [512][128]
    unsigned short* w2t = w1t + (size_t)512 * 128;                     // [1024][512]
    unsigned short* X   = w2t + (size_t)1024 * 512;                    // [30720][128]
    unsigned short* Y1  = X   + (size_t)MROWS * 128;                   // [30720][512]

    k_prep<<<144 + 8192, 256, 0, stream>>>(W1, W2, w1t, w2t, s1, keys, mkey);
    k_scan<<<P_N * SPLIT, 256, 0, stream>>>(end_pos, rel_pos, bpts, keys);
    k_assemble<<<P_N, 256, 0, stream>>>(keys, end_pos, rel_pos, bpts, Wsp, bsp, h, X);
    k_gemm256<128, true><<<(MROWS / 256) * (512 / 256), 512, 0, stream>>>(
        X, w1t, b1, Y1, 512, s1, q1, nullptr);
    k_bnrelu<<<MROWS / 32, 256, 0, stream>>>(Y1, s1, q1, g1, be1);
    k_gemm256<512, false><<<(MROWS / 256) * (1024 / 256), 512, 0, stream>>>(
        Y1, w2t, b2, nullptr, 1024, s2, q2, mkey);
    k_bnfin<<<(P_N * 128) / 256, 256, 0, stream>>>(mkey, s2, q2, g2, be2, out);
}

// Round 10
// 144.280 us; speedup vs baseline: 1.4815x; 1.0812x over previous
//
#include <hip/hip_runtime.h>
#include <hip/hip_bf16.h>
#include <math.h>

#define P_N   2048
#define B_N   10000
#define NB    15
#define MROWS (P_N * NB)   // 30720
#define SPLIT 5
#define BPB   (B_N / SPLIT)  // 2000 boundary points per scan block

typedef __bf16 bf16x8 __attribute__((ext_vector_type(8)));
typedef float  f32x4  __attribute__((ext_vector_type(4)));

__device__ __forceinline__ float bf2f(unsigned short u) {
    union { unsigned int i; float f; } v; v.i = ((unsigned int)u) << 16; return v.f;
}
__device__ __forceinline__ unsigned short f2bf(float f) {
    union { float f; unsigned int i; } v; v.f = f;
    unsigned int i = v.i;
    i += 0x7FFFu + ((i >> 16) & 1u);
    return (unsigned short)(i >> 16);
}
__device__ __forceinline__ void gld_lds16(const unsigned short* g, unsigned short* l) {
    __builtin_amdgcn_global_load_lds(
        (const __attribute__((address_space(1))) unsigned int*)g,
        (__attribute__((address_space(3))) unsigned int*)l, 16, 0, 0);
}
// monotone u32 key for f32 (x<y iff key(x)<key(y)); all real keys > 0
__device__ __forceinline__ unsigned fkey(float f) {
    unsigned b = __float_as_uint(f);
    return (b & 0x80000000u) ? ~b : (b | 0x80000000u);
}
__device__ __forceinline__ float funkey(unsigned key) {
    unsigned b = (key & 0x80000000u) ? (key ^ 0x80000000u) : ~key;
    return __uint_as_float(b);
}

// ---- K0: tiled transpose W1/W2 -> bf16 [N][K]; zero stats/keys/maxkeys ------
__global__ __launch_bounds__(256) void k_prep(const float* __restrict__ W1,
        const float* __restrict__ W2, unsigned short* __restrict__ w1t,
        unsigned short* __restrict__ w2t, float* __restrict__ stats,
        unsigned long long* __restrict__ keys, unsigned int* __restrict__ mkey) {
    int blk = blockIdx.x, tid = threadIdx.x;
    if (blk < 144) {
        __shared__ unsigned short t[64][65];
        const float* W; unsigned short* O; int NC, K, tr, tc;
        if (blk < 16) { W = W1; O = w1t; NC = 512; K = 128; tr = blk & 1; tc = blk >> 1; }
        else { int b = blk - 16; W = W2; O = w2t; NC = 1024; K = 512; tr = b & 7; tc = b >> 3; }
        int r0 = tr * 64, c0 = tc * 64;
        int cx = tid & 63, rg = tid >> 6;
#pragma unroll
        for (int i = 0; i < 16; ++i) {
            int r = rg * 16 + i;
            t[r][cx] = f2bf(W[(size_t)(r0 + r) * NC + c0 + cx]);
        }
        __syncthreads();
#pragma unroll
        for (int i = 0; i < 16; ++i) {
            int n = rg * 16 + i;
            O[(size_t)(c0 + n) * K + r0 + cx] = t[cx][n];
        }
    } else {
        int idx = (blk - 144) * 256 + tid;        // 8192 blocks: 2M mkey + misc
        if (idx < P_N * 1024) mkey[idx] = 0u;     // 0 < fkey(any real)
        if (idx < MROWS) keys[idx] = ~0ull;
        if (idx < 3072) stats[idx] = 0.0f;
    }
}

// ---- K1a: scan boundary points, per-bin min via packed u64 atomicMin --------
__global__ __launch_bounds__(256) void k_scan(
        const float* __restrict__ end_pos, const float* __restrict__ rel_pos,
        const float* __restrict__ bpts, unsigned long long* __restrict__ keys) {
    __shared__ unsigned long long s_key[NB];
    int tid = threadIdx.x;
    int p = blockIdx.x / SPLIT, part = blockIdx.x % SPLIT;
    if (tid < NB) s_key[tid] = ~0ull;
    __syncthreads();

    float ex = end_pos[2 * p], ey = end_pos[2 * p + 1];
    float rx = rel_pos[2 * p], ry = rel_pos[2 * p + 1];
    float rr = rx * rx + ry * ry;
    float c, s;
    if (rr > 0.0f) { float inv = 1.0f / sqrtf(rr); c = rx * inv; s = ry * inv; }
    else           { c = 1.0f; s = 0.0f; }

    const float T0 = -4.704630109f, T1 = -2.246036774f, T2 = -1.376381920f,
                T3 = -0.900404044f, T4 = -0.577350269f, T5 = -0.324919696f,
                T6 = -0.105104235f, T7 =  0.105104235f, T8 =  0.324919696f,
                T9 =  0.577350269f, T10 = 0.900404044f, T11 = 1.376381920f,
                T12 = 2.246036774f, T13 = 4.704630109f;

    const float2* bp2 = (const float2*)bpts;
    int bstart = part * BPB;
    for (int b = bstart + tid; b < bstart + BPB; b += 256) {
        float2 pt = bp2[b];
        float dx = pt.x - ex, dy = pt.y - ey;
        float xb = dx * c + dy * s;
        float yb = dy * c - dx * s;
        float r2 = xb * xb + yb * yb;
        bool v3 = yb > T7 * xb;
        float ta = v3 ? T11 : T3;
        bool v2 = yb > ta * xb;
        float tb = v3 ? (v2 ? T13 : T9) : (v2 ? T5 : T1);
        bool v1 = yb > tb * xb;
        float tc = v3 ? (v2 ? (v1 ? 3.0e38f : T12) : (v1 ? T10 : T8))
                      : (v2 ? (v1 ? T6 : T4)       : (v1 ? T2 : T0));
        bool v0 = yb > tc * xb;
        int bin = (v3 ? 8 : 0) + (v2 ? 4 : 0) + (v1 ? 2 : 0) + (v0 ? 1 : 0);
        if (xb > 0.0f) {
            unsigned long long key =
                ((unsigned long long)__float_as_uint(r2) << 32) | (unsigned int)b;
            atomicMin(&s_key[bin], key);
        }
    }
    __syncthreads();
    if (tid < NB) atomicMin(&keys[p * NB + tid], s_key[tid]);
}

// ---- K1b: choose point/fallback, build X = [emb(64) | h(64)] per (p,cell) ---
__global__ __launch_bounds__(256) void k_assemble(
        const unsigned long long* __restrict__ keys,
        const float* __restrict__ end_pos, const float* __restrict__ rel_pos,
        const float* __restrict__ bpts, const float* __restrict__ Wsp,
        const float* __restrict__ bsp, const float* __restrict__ h,
        unsigned short* __restrict__ X) {
    __shared__ float2 s_rel[NB];
    int p = blockIdx.x, tid = threadIdx.x;
    if (tid < NB) {
        float ex = end_pos[2 * p], ey = end_pos[2 * p + 1];
        unsigned long long key = keys[p * NB + tid];
        float r = sqrtf(__uint_as_float((unsigned int)(key >> 32)));
        float relx, rely;
        if (r <= 2.0f) {
            int b = (int)(key & 0xFFFFFFFFu);
            relx = bpts[2 * b] - ex; rely = bpts[2 * b + 1] - ey;
        } else {
            float rx = rel_pos[2 * p], ry = rel_pos[2 * p + 1];
            float rr = rx * rx + ry * ry;
            float c, s;
            if (rr > 0.0f) { float inv = 1.0f / sqrtf(rr); c = rx * inv; s = ry * inv; }
            else           { c = 1.0f; s = 0.0f; }
            float th = ((float)tid + 0.5f) * (float)(M_PI / 15.0) - (float)(M_PI / 2.0);
            float xc = 2.0f * cosf(th), yc = 2.0f * sinf(th);
            relx = xc * c - yc * s;
            rely = xc * s + yc * c;
        }
        s_rel[tid] = make_float2(relx, rely);
    }
    __syncthreads();
    if (tid < NB * 16) {
        int cell = tid >> 4, e0 = (tid & 15) * 8;
        float2 rel = s_rel[cell];
        unsigned short ubuf[8];
        if (e0 < 64) {
            float4 w0a = *(const float4*)(Wsp + e0),      w0b = *(const float4*)(Wsp + e0 + 4);
            float4 w1a = *(const float4*)(Wsp + 64 + e0), w1b = *(const float4*)(Wsp + 64 + e0 + 4);
            float4 bba = *(const float4*)(bsp + e0),      bbb = *(const float4*)(bsp + e0 + 4);
            float w0[8] = {w0a.x,w0a.y,w0a.z,w0a.w,w0b.x,w0b.y,w0b.z,w0b.w};
            float w1[8] = {w1a.x,w1a.y,w1a.z,w1a.w,w1b.x,w1b.y,w1b.z,w1b.w};
            float bb[8] = {bba.x,bba.y,bba.z,bba.w,bbb.x,bbb.y,bbb.z,bbb.w};
#pragma unroll
            for (int j = 0; j < 8; ++j)
                ubuf[j] = f2bf(rel.x * w0[j] + rel.y * w1[j] + bb[j]);
        } else {
            float4 ha = *(const float4*)(h + p * 64 + (e0 - 64));
            float4 hb = *(const float4*)(h + p * 64 + (e0 - 64) + 4);
            float hv[8] = {ha.x,ha.y,ha.z,ha.w,hb.x,hb.y,hb.z,hb.w};
#pragma unroll
            for (int j = 0; j < 8; ++j) ubuf[j] = f2bf(hv[j]);
        }
        *(uint4*)(X + ((size_t)p * NB + cell) * 128 + e0) = *(uint4*)ubuf;
    }
}

// ---- 256x256 GEMM, BK=32, 8 waves (2Mx4N), 3-buf distance-2 counted-vmcnt
//      pipeline, 2 phases/K-step with setprio'd MFMA clusters.
// Invariants: stage(t+2) issued during step t (2 loads/phase/wave);
//   end-of-step wait vmcnt(4) keeps t+2's 4 loads in flight while
//   guaranteeing t+1's are in LDS; one barrier per K-step (ds_reads are
//   register-consumed before it; buf[(t+2)%3]'s readers finished at step t-1).
template<int K, bool WRITE_C>
__global__ __launch_bounds__(512) void k_gemm256(
        const unsigned short* __restrict__ A, const unsigned short* __restrict__ Bt,
        const float* __restrict__ bias, unsigned short* __restrict__ C,
        int N, float* __restrict__ osum, float* __restrict__ osq,
        unsigned int* __restrict__ mkey) {
    __shared__ __align__(16) unsigned short lds[49152];  // 3 bufs x 16384 (A|B)
    int tid = threadIdx.x;

    // XCD-grouped remap: blocks sharing an A-panel sit on one XCD's L2
    int nbt = N >> 8;
    int d = blockIdx.x;
    int m5 = d >> 3;
    int bn = m5 % nbt;
    int bm = (d & 7) + ((m5 / nbt) << 3);
    int row0 = bm << 8, col0 = bn << 8;

    int lane = tid & 63, wave = tid >> 6;
    int wr = wave >> 2, wc = wave & 3;
    int frow = lane & 15, kq = lane >> 4;

    f32x4 zero = {0.f, 0.f, 0.f, 0.f};
    f32x4 acc[8][4];
#pragma unroll
    for (int i = 0; i < 8; ++i)
#pragma unroll
        for (int j = 0; j < 4; ++j) acc[i][j] = zero;

    // staging: waves 0-3 stage A rows [w*64, w*64+64), waves 4-7 stage B rows.
    // chunk = 16 rows x 32 k in [kseg][row][8] (1KB, linear in lane order).
    const unsigned short* gsrc =
        (wave < 4) ? (A  + (size_t)(row0 + (wave << 6) + frow) * K + kq * 8)
                   : (Bt + (size_t)(col0 + ((wave - 4) << 6) + frow) * K + kq * 8);
    unsigned ldsbase = (unsigned)wave * 2048;   // waves 4-7 land in B region 8192+

    auto issue_half = [&](int t, int hf) {   // 2 gld_lds per wave
        unsigned short* dst = lds + (t % 3) * 16384 + ldsbase + hf * 1024;
        int ko = t * 32;
        gld_lds16(gsrc + ko + (size_t)(hf * 32) * K,      dst);
        gld_lds16(gsrc + ko + (size_t)(hf * 32 + 16) * K, dst + 512);
    };

    constexpr int NT = K / 32;
    static_assert(NT >= 2, "need >=2 K-tiles");

    // prologue: tiles 0 and 1 in flight; wait tile 0 only
    issue_half(0, 0); issue_half(0, 1);
    issue_half(1, 0); issue_half(1, 1);
    asm volatile("s_waitcnt vmcnt(4)" ::: "memory");
    __builtin_amdgcn_s_barrier();
    asm volatile("" ::: "memory");

#pragma unroll
    for (int t = 0; t < NT; ++t) {
        const unsigned short* buf = lds + (t % 3) * 16384;
        bf16x8 af[8], bfv[4];
        // ---- phase 1: issue half 0 of tile t+2; compute i = 0..3 ----
        if (t + 2 < NT) issue_half(t + 2, 0);
#pragma unroll
        for (int j = 0; j < 4; ++j)
            bfv[j] = *(const bf16x8*)&buf[8192 + (wc * 4 + j) * 512 + kq * 128 + frow * 8];
#pragma unroll
        for (int i = 0; i < 4; ++i)
            af[i] = *(const bf16x8*)&buf[(wr * 8 + i) * 512 + kq * 128 + frow * 8];
        __builtin_amdgcn_s_setprio(1);
#pragma unroll
        for (int i = 0; i < 4; ++i)
#pragma unroll
            for (int j = 0; j < 4; ++j)
                acc[i][j] = __builtin_amdgcn_mfma_f32_16x16x32_bf16(af[i], bfv[j], acc[i][j], 0, 0, 0);
        __builtin_amdgcn_s_setprio(0);
        // ---- phase 2: issue half 1 of tile t+2; compute i = 4..7 ----
        if (t + 2 < NT) issue_half(t + 2, 1);
#pragma unroll
        for (int i = 4; i < 8; ++i)
            af[i] = *(const bf16x8*)&buf[(wr * 8 + i) * 512 + kq * 128 + frow * 8];
        __builtin_amdgcn_s_setprio(1);
#pragma unroll
        for (int i = 4; i < 8; ++i)
#pragma unroll
            for (int j = 0; j < 4; ++j)
                acc[i][j] = __builtin_amdgcn_mfma_f32_16x16x32_bf16(af[i], bfv[j], acc[i][j], 0, 0, 0);
        __builtin_amdgcn_s_setprio(0);
        // ---- boundary: tile t+1 landed; tile t+2's 4 loads stay in flight ----
        if (t + 2 < NT) asm volatile("s_waitcnt vmcnt(4)" ::: "memory");
        else            asm volatile("s_waitcnt vmcnt(0)" ::: "memory");
        __builtin_amdgcn_s_barrier();
        asm volatile("" ::: "memory");
    }

    // ---- fused column stats (f32, pre-rounding) ----
    float bv[4];
#pragma unroll
    for (int j = 0; j < 4; ++j) bv[j] = bias[col0 + wc * 64 + j * 16 + frow];

#pragma unroll
    for (int j = 0; j < 4; ++j) {
        int col = col0 + wc * 64 + j * 16 + frow;
        float csum = 0.f, csq = 0.f;
#pragma unroll
        for (int i = 0; i < 8; ++i) {
#pragma unroll
            for (int r = 0; r < 4; ++r) {
                float y = acc[i][j][r] + bv[j];
                csum += y; csq = fmaf(y, y, csq);
            }
        }
        csum += __shfl_xor(csum, 16); csum += __shfl_xor(csum, 32);
        csq  += __shfl_xor(csq, 16);  csq  += __shfl_xor(csq, 32);
        if (lane < 16) { atomicAdd(&osum[col], csum); atomicAdd(&osq[col], csq); }
    }

    // ---- 4 bands of 64 rows: stage bf16(y) in LDS [64][264], then either
    //      coalesced C store (GEMM1) or per-ped max scan (GEMM2) ----
    unsigned short* ldsC = lds;     // 64*264 elems = 33 KB, main loop done
#pragma unroll
    for (int b = 0; b < 4; ++b) {
        __syncthreads();
        if (wr == (b >> 1)) {
#pragma unroll
            for (int j = 0; j < 4; ++j) {
#pragma unroll
                for (int ii = 0; ii < 4; ++ii) {
                    int i = (b & 1) * 4 + ii;
#pragma unroll
                    for (int r = 0; r < 4; ++r) {
                        float y = acc[i][j][r] + bv[j];
                        ldsC[(ii * 16 + kq * 4 + r) * 264 + wc * 64 + j * 16 + frow] = f2bf(y);
                    }
                }
            }
        }
        __syncthreads();
        if (WRITE_C) {
#pragma unroll
            for (int it = 0; it < 4; ++it) {
                int s = it * 512 + tid;          // 2048 uint4 = 64 rows x 256 cols
                int brow = s >> 5, seg = s & 31;
                *(uint4*)(C + (size_t)(row0 + b * 64 + brow) * N + col0 + seg * 8) =
                    *(const uint4*)&ldsC[brow * 264 + seg * 8];
            }
        } else {
            int col = tid & 255, half = tid >> 8;  // 2 threads per column
            int lrow0 = half * 32;
            int grow = row0 + b * 64 + lrow0;
            int curp = grow / 15;
            int rem = 15 - (grow - curp * 15);     // rows until ped boundary
            float mx = -3.0e38f;
#pragma unroll
            for (int r = 0; r < 32; ++r) {
                mx = fmaxf(mx, bf2f(ldsC[(lrow0 + r) * 264 + col]));
                if (--rem == 0) {
                    atomicMax(&mkey[(size_t)curp * 1024 + col0 + col], fkey(mx));
                    mx = -3.0e38f; ++curp; rem = 15;
                }
            }
            if (rem != 15)
                atomicMax(&mkey[(size_t)curp * 1024 + col0 + col], fkey(mx));
        }
    }
}

// ---- BN + ReLU, in place, column-resident streaming (N=512); inline coeffs --
__global__ __launch_bounds__(256) void k_bnrelu(unsigned short* __restrict__ Y,
        const float* __restrict__ s, const float* __restrict__ q,
        const float* __restrict__ g, const float* __restrict__ be) {
    int tid = threadIdx.x;
    int seg  = tid & 63;                 // 64 uint4 segments per 512-col row
    int roff = tid >> 6;                 // 4 row-phases
    int r0 = blockIdx.x * 32;
    int c0 = seg * 8;
    const float invN = 1.0f / (float)MROWS;
    float scv[8], shv[8];
#pragma unroll
    for (int j = 0; j < 8; ++j) {
        float m = s[c0 + j] * invN;
        float v = q[c0 + j] * invN - m * m;
        float k = g[c0 + j] * rsqrtf(v + 1e-5f);
        scv[j] = k; shv[j] = be[c0 + j] - m * k;
    }
    for (int r = r0 + roff; r < r0 + 32; r += 4) {
        unsigned short* p = Y + (size_t)r * 512 + c0;
        uint4 v = *(const uint4*)p;
        unsigned short* u = (unsigned short*)&v;
#pragma unroll
        for (int j = 0; j < 8; ++j) {
            float x = fmaf(bf2f(u[j]), scv[j], shv[j]);
            u[j] = f2bf(fmaxf(x, 0.0f));
        }
        *(uint4*)p = v;
    }
}

// ---- finalize: out = relu(sc2 * max_y + sh2) from u32-keyed maxima ----------
__global__ void k_bnfin(const unsigned int* __restrict__ mkey, const float* __restrict__ s2,
                        const float* __restrict__ q2, const float* __restrict__ g2,
                        const float* __restrict__ be2, float* __restrict__ out) {
    int idx = blockIdx.x * 256 + threadIdx.x;      // 2048*128 threads
    int p = idx >> 7, cb = idx & 127;
    int c0 = cb << 3;
    const float invN = 1.0f / (float)MROWS;
    float4 sa = *(const float4*)(s2 + c0),  sb = *(const float4*)(s2 + c0 + 4);
    float4 qa = *(const float4*)(q2 + c0),  qb = *(const float4*)(q2 + c0 + 4);
    float4 ga = *(const float4*)(g2 + c0),  gb = *(const float4*)(g2 + c0 + 4);
    float4 ea = *(const float4*)(be2 + c0), eb = *(const float4*)(be2 + c0 + 4);
    float sv[8] = {sa.x,sa.y,sa.z,sa.w,sb.x,sb.y,sb.z,sb.w};
    float qv[8] = {qa.x,qa.y,qa.z,qa.w,qb.x,qb.y,qb.z,qb.w};
    float gv[8] = {ga.x,ga.y,ga.z,ga.w,gb.x,gb.y,gb.z,gb.w};
    float ev[8] = {ea.x,ea.y,ea.z,ea.w,eb.x,eb.y,eb.z,eb.w};
    uint4 k0 = *(const uint4*)(mkey + (size_t)p * 1024 + c0);
    uint4 k1 = *(const uint4*)(mkey + (size_t)p * 1024 + c0 + 4);
    unsigned kv[8] = {k0.x,k0.y,k0.z,k0.w,k1.x,k1.y,k1.z,k1.w};
    float o[8];
#pragma unroll
    for (int j = 0; j < 8; ++j) {
        float m = sv[j] * invN;
        float v = qv[j] * invN - m * m;
        float k = gv[j] * rsqrtf(v + 1e-5f);
        float sh = ev[j] - m * k;
        o[j] = fmaxf(fmaf(funkey(kv[j]), k, sh), 0.0f);
    }
    float4 o0 = {o[0], o[1], o[2], o[3]};
    float4 o1 = {o[4], o[5], o[6], o[7]};
    *(float4*)(out + (size_t)p * 1024 + c0)     = o0;
    *(float4*)(out + (size_t)p * 1024 + c0 + 4) = o1;
}

extern "C" void kernel_launch(void* const* d_in, const int* in_sizes, int n_in,
                              void* d_out, int out_size, void* d_ws, size_t ws_size,
                              hipStream_t stream) {
    const float* h       = (const float*)d_in[0];
    const float* end_pos = (const float*)d_in[1];
    const float* rel_pos = (const float*)d_in[2];
    const float* bpts    = (const float*)d_in[3];
    const float* Wsp     = (const float*)d_in[4];
    const float* bsp     = (const float*)d_in[5];
    const float* W1      = (const float*)d_in[6];
    const float* b1      = (const float*)d_in[7];
    const float* g1      = (const float*)d_in[8];
    const float* be1     = (const float*)d_in[9];
    const float* W2      = (const float*)d_in[10];
    const float* b2      = (const float*)d_in[11];
    const float* g2      = (const float*)d_in[12];
    const float* be2     = (const float*)d_in[13];
    float* out = (float*)d_out;

    char* ws = (char*)d_ws;
    float* s1  = (float*)ws;                 // 3072 f32 zeroed by k_prep
    float* q1  = s1 + 512;
    float* s2  = q1 + 512;
    float* q2  = s2 + 1024;
    unsigned long long* keys = (unsigned long long*)(ws + 32768);      // [30720] u64
    unsigned int* mkey = (unsigned int*)(ws + 32768 + 245760);         // [2048*1024] u32
    unsigned short* w1t = (unsigned short*)(ws + 32768 + 245760 + 8388608); // [512][128]
    unsigned short* w2t = w1t + (size_t)512 * 128;                     // [1024][512]
    unsigned short* X   = w2t + (size_t)1024 * 512;                    // [30720][128]
    unsigned short* Y1  = X   + (size_t)MROWS * 128;                   // [30720][512]

    k_prep<<<144 + 8192, 256, 0, stream>>>(W1, W2, w1t, w2t, s1, keys, mkey);
    k_scan<<<P_N * SPLIT, 256, 0, stream>>>(end_pos, rel_pos, bpts, keys);
    k_assemble<<<P_N, 256, 0, stream>>>(keys, end_pos, rel_pos, bpts, Wsp, bsp, h, X);
    k_gemm256<128, true><<<(MROWS / 256) * (512 / 256), 512, 0, stream>>>(
        X, w1t, b1, Y1, 512, s1, q1, nullptr);
    k_bnrelu<<<MROWS / 32, 256, 0, stream>>>(Y1, s1, q1, g1, be1);
    k_gemm256<512, false><<<(MROWS / 256) * (1024 / 256), 512, 0, stream>>>(
        Y1, w2t, b2, nullptr, 1024, s2, q2, mkey);
    k_bnfin<<<(P_N * 128) / 256, 256, 0, stream>>>(mkey, s2, q2, g2, be2, out);
}